// Round 15
// baseline (206.053 us; speedup 1.0000x reference)
//
#include <hip/hip_runtime.h>
#include <math.h>

#define PI_F      3.141592653f
#define TWO_PI_F  6.283185306f
#define HALF_PI_F 1.5707963265f
#define IOU_THR_F 0.1f
#define ROUNDS_MAX 16
#define NBLK_MIS   8

typedef unsigned long long u64;

__device__ __forceinline__ float limit_period_f(float v) {
    return v - floorf(v / TWO_PI_F + 0.5f) * TWO_PI_F;
}

__device__ __forceinline__ u64 shfl_u64(u64 v, int src) {
    unsigned int lo = (unsigned int)(v & 0xffffffffull);
    unsigned int hi = (unsigned int)(v >> 32);
    lo = __shfl((int)lo, src);
    hi = __shfl((int)hi, src);
    return ((u64)hi << 32) | (u64)lo;
}

// Agent-scope grid barrier (R9/R10-validated pattern).
__device__ __forceinline__ void gridbar(int* cnt, int* gen, int target, int nblk) {
    __syncthreads();
    if (threadIdx.x == 0) {
        __threadfence();
        int prev = __hip_atomic_fetch_add(cnt, 1, __ATOMIC_ACQ_REL, __HIP_MEMORY_SCOPE_AGENT);
        if (prev == nblk - 1) {
            __hip_atomic_store(cnt, 0, __ATOMIC_RELAXED, __HIP_MEMORY_SCOPE_AGENT);
            __hip_atomic_fetch_add(gen, 1, __ATOMIC_ACQ_REL, __HIP_MEMORY_SCOPE_AGENT);
        } else {
            while (__hip_atomic_load(gen, __ATOMIC_ACQUIRE, __HIP_MEMORY_SCOPE_AGENT) < target)
                __builtin_amdgcn_s_sleep(2);
        }
        __threadfence();
    }
    __syncthreads();
}

// ---------------- Kernel 1: adjacency + occByte + control-var init ------------
// Thread owns (row i, word w): 64 in-register IoUs vs LDS-staged j-boxes.
// adjC[(size_t)w * n + i] = word w of row i.
// occByte[rb*64 + w] = 1 iff any row in block rb has nonzero word w.
// Block (0,0) zeroes the mis control vars (no other block touches them).
__global__ void adj_kernel(const float* __restrict__ boxes,
                           u64* __restrict__ adjC,
                           unsigned char* __restrict__ occByte,
                           int* __restrict__ ctrl,   // {bcnt, bgen, unresolved[ROUNDS_MAX]}
                           int n, int words) {
    __shared__ float jS[7][64];
    int w = blockIdx.x;
    int tid = threadIdx.x;              // 256 = 4 waves
    int lane = tid & 63, wv = tid >> 6;
    if (blockIdx.x == 0 && blockIdx.y == 0 && tid < 2 + ROUNDS_MAX) ctrl[tid] = 0;
    if (tid < 64) {
        int j = (w << 6) + tid;
        if (j < n) {
            float b0 = boxes[j*7+0], b1 = boxes[j*7+1], b2 = boxes[j*7+2];
            float b3 = boxes[j*7+3], b4 = boxes[j*7+4], b5 = boxes[j*7+5];
            jS[0][tid] = b0 - b5*0.5f;  jS[3][tid] = b0 + b5*0.5f;
            jS[1][tid] = b1 - b4*0.5f;  jS[4][tid] = b1 + b4*0.5f;
            jS[2][tid] = b2 - b3*0.5f;  jS[5][tid] = b2 + b3*0.5f;
            jS[6][tid] = (b5*b4)*b3;
        }
    }
    __syncthreads();
    int i = blockIdx.y * 256 + tid;
    u64 word = 0ull;
    if (i < n) {
        float b0 = boxes[i*7+0], b1 = boxes[i*7+1], b2 = boxes[i*7+2];
        float b3 = boxes[i*7+3], b4 = boxes[i*7+4], b5 = boxes[i*7+5];
        float lix = b0 - b5*0.5f, hix = b0 + b5*0.5f;
        float liy = b1 - b4*0.5f, hiy = b1 + b4*0.5f;
        float liz = b2 - b3*0.5f, hiz = b2 + b3*0.5f;
        float vi  = (b5*b4)*b3;
        int jmax = n - (w << 6); if (jmax > 64) jmax = 64;
        for (int jj = 0; jj < jmax; ++jj) {
            float ix = fminf(hix, jS[3][jj]) - fmaxf(lix, jS[0][jj]); ix = fmaxf(ix, 0.0f);
            float iy = fminf(hiy, jS[4][jj]) - fmaxf(liy, jS[1][jj]); iy = fmaxf(iy, 0.0f);
            float iz = fminf(hiz, jS[5][jj]) - fmaxf(liz, jS[2][jj]); iz = fmaxf(iz, 0.0f);
            float inter = (ix*iy)*iz;
            float u = fmaxf(vi + jS[6][jj] - inter, 1e-8f);
            bool pred = (inter / u) > IOU_THR_F;
            word |= ((u64)(pred ? 1 : 0)) << jj;
        }
        adjC[(size_t)w * n + i] = word;
    }
    u64 bal = __ballot((i < n) && word != 0ull);
    int rb = blockIdx.y * 4 + wv;
    if (lane == 0 && rb < 64)
        occByte[rb * 64 + w] = bal ? (unsigned char)1 : (unsigned char)0;
}

// ---------------- Kernel 2: Jacobi/GS hybrid MIS (8 blocks) + indices ---------
// seed(i) <=> no earlier neighbor of i is a seed. Block g owns words
// [8g,8g+8): in-block Gauss-Seidel (8 syncthreads substeps, S/R in LDS);
// cross-block Jacobi via per-round global snapshot + small grid barrier.
// Rows preloaded to registers (occ-masked). Early-exit on convergence.
// Then: indices[j] = rank of max-index adjacent seed; seedList; nclust.
__global__ __launch_bounds__(512) void mis_kernel(
        const u64* __restrict__ adjC,
        const unsigned char* __restrict__ occByte,
        u64* __restrict__ S, u64* __restrict__ R,
        int* __restrict__ indices,
        int* __restrict__ seedList,
        int* __restrict__ nclust,
        int* __restrict__ ctrl,     // {bcnt, bgen, unresolved[ROUNDS_MAX]}
        int n, int words) {
    __shared__ u64 occL[64];
    __shared__ u64 S_l[8], R_l[8];
    __shared__ u64 smS[64];
    __shared__ int wsS[64];
    int g = blockIdx.x;            // NBLK_MIS blocks
    int tid = threadIdx.x;         // 512 = 8 waves
    int lane = tid & 63, wv = tid >> 6;
    int* bcnt = ctrl;
    int* bgen = ctrl + 1;
    int* unres = ctrl + 2;

    // occL[rb] via ballots (mask to valid words)
    u64 wmask = (words >= 64) ? ~0ull : ((1ull << words) - 1ull);
    for (int rb = wv; rb < 64; rb += 8) {
        unsigned char b = occByte[rb * 64 + lane];
        u64 m = __ballot(b != 0) & wmask;
        if (lane == 0) occL[rb] = m;
    }
    __syncthreads();

    int w = (g << 3) + wv;
    bool wactive = (w < words);
    int base = w << 6;
    int vb = n - base;
    u64 valid = wactive ? ((vb >= 64) ? ~0ull : ((vb <= 0) ? 0ull : ((1ull << vb) - 1ull))) : 0ull;
    int i = base + lane;
    bool ld = wactive && (i < n);

    // preload rows: diagonal + up to 6 occ'd earlier words (wave-uniform e's)
    u64 Adiag = ld ? adjC[(size_t)w * n + i] : 0ull;
    u64 occE = wactive ? (occL[w] & (w ? ((1ull << w) - 1ull) : 0ull)) : 0ull;
    int e0=-1,e1=-1,e2=-1,e3=-1,e4=-1,e5=-1;
    u64 t = occE;
    if (t) { e0 = (int)__ffsll(t) - 1; t &= t - 1; }
    if (t) { e1 = (int)__ffsll(t) - 1; t &= t - 1; }
    if (t) { e2 = (int)__ffsll(t) - 1; t &= t - 1; }
    if (t) { e3 = (int)__ffsll(t) - 1; t &= t - 1; }
    if (t) { e4 = (int)__ffsll(t) - 1; t &= t - 1; }
    if (t) { e5 = (int)__ffsll(t) - 1; t &= t - 1; }
    u64 rest = t;
    u64 r0 = (e0 >= 0 && ld) ? adjC[(size_t)e0 * n + i] : 0ull;
    u64 r1 = (e1 >= 0 && ld) ? adjC[(size_t)e1 * n + i] : 0ull;
    u64 r2 = (e2 >= 0 && ld) ? adjC[(size_t)e2 * n + i] : 0ull;
    u64 r3 = (e3 >= 0 && ld) ? adjC[(size_t)e3 * n + i] : 0ull;
    u64 r4 = (e4 >= 0 && ld) ? adjC[(size_t)e4 * n + i] : 0ull;
    u64 r5 = (e5 >= 0 && ld) ? adjC[(size_t)e5 * n + i] : 0ull;

    // init own S/R (LDS + global), then sync all blocks
    if (lane == 0 && wactive) {
        S_l[wv] = 0ull; R_l[wv] = ~valid;
        __hip_atomic_store(&S[w], 0ull,   __ATOMIC_RELAXED, __HIP_MEMORY_SCOPE_AGENT);
        __hip_atomic_store(&R[w], ~valid, __ATOMIC_RELAXED, __HIP_MEMORY_SCOPE_AGENT);
    }
    gridbar(bcnt, bgen, 1, NBLK_MIS);

    for (int r = 0; r < ROUNDS_MAX; ++r) {
        // cross-block snapshot: lane e holds word e's S/R
        u64 S_snap = __hip_atomic_load(&S[lane], __ATOMIC_RELAXED, __HIP_MEMORY_SCOPE_AGENT);
        u64 R_snap = __hip_atomic_load(&R[lane], __ATOMIC_RELAXED, __HIP_MEMORY_SCOPE_AGENT);
        // in-block Gauss-Seidel: words resolve in ascending order
        for (int k = 0; k < 8; ++k) {
            if (wv == k && wactive) {
                u64 Rw = R_l[wv];
                u64 unknownIn = valid & ~Rw;
                if (unknownIn != 0ull) {
                    u64 sA = 0ull, uA = 0ull;
                    #define ACC(E, RR) if (E >= 0) { \
                        u64 Se, Re; \
                        if ((E >> 3) == g) { Se = S_l[E & 7]; Re = R_l[E & 7]; } \
                        else { Se = shfl_u64(S_snap, E); Re = shfl_u64(R_snap, E); } \
                        sA |= (RR) & Se; uA |= (RR) & ~Re; }
                    ACC(e0, r0) ACC(e1, r1) ACC(e2, r2)
                    ACC(e3, r3) ACC(e4, r4) ACC(e5, r5)
                    #undef ACC
                    u64 rr = rest;
                    while (rr) {
                        int e = (int)__ffsll(rr) - 1; rr &= rr - 1;
                        u64 row = ld ? adjC[(size_t)e * n + i] : 0ull;
                        u64 Se, Re;
                        if ((e >> 3) == g) { Se = S_l[e & 7]; Re = R_l[e & 7]; }
                        else { Se = shfl_u64(S_snap, e); Re = shfl_u64(R_snap, e); }
                        sA |= row & Se; uA |= row & ~Re;
                    }
                    u64 E_seen  = __ballot(sA != 0ull);
                    u64 Unk_ext = __ballot(uA != 0ull);
                    u64 newSeed = S_l[wv];
                    u64 newRes  = Rw;
                    u64 pending = unknownIn;
                    while (pending) {
                        int b = (int)__ffsll(pending) - 1;
                        pending &= pending - 1;
                        u64 rowb = shfl_u64(Adiag, b);
                        u64 below = b ? ((1ull << b) - 1ull) : 0ull;
                        u64 earlier = rowb & below;
                        u64 bit = 1ull << b;
                        bool eSeen = (E_seen >> b) & 1ull;
                        bool eUnk  = (Unk_ext >> b) & 1ull;
                        if (eSeen || (earlier & newSeed)) {
                            newRes |= bit;                      // nonseed
                        } else if (eUnk || (earlier & ~newRes)) {
                            // blocked: unresolved earlier neighbor
                        } else {
                            newSeed |= bit; newRes |= bit;      // seed
                        }
                    }
                    if (lane == 0) { S_l[wv] = newSeed; R_l[wv] = newRes; }
                }
            }
            __syncthreads();
        }
        // publish + convergence count
        if (lane == 0 && wactive) {
            __hip_atomic_store(&S[w], S_l[wv], __ATOMIC_RELAXED, __HIP_MEMORY_SCOPE_AGENT);
            __hip_atomic_store(&R[w], R_l[wv], __ATOMIC_RELAXED, __HIP_MEMORY_SCOPE_AGENT);
            if (R_l[wv] != valid)
                __hip_atomic_fetch_add(&unres[r], 1, __ATOMIC_ACQ_REL, __HIP_MEMORY_SCOPE_AGENT);
        }
        gridbar(bcnt, bgen, r + 2, NBLK_MIS);
        int unc = __hip_atomic_load(&unres[r], __ATOMIC_ACQUIRE, __HIP_MEMORY_SCOPE_AGENT);
        if (unc == 0) break;                     // uniform across all blocks
    }

    // ---- indices / seedList / nclust (final S; disjoint j ranges) ----
    if (tid < 64) {
        smS[tid] = (tid < words) ? __hip_atomic_load(&S[tid], __ATOMIC_RELAXED, __HIP_MEMORY_SCOPE_AGENT) : 0ull;
    }
    __syncthreads();
    if (tid < 64) {
        int pc = (int)__popcll(smS[tid]);
        int x = pc;
        for (int o = 1; o < 64; o <<= 1) {
            int y = __shfl_up(x, o);
            if (tid >= o) x += y;
        }
        wsS[tid] = x - pc;                        // exclusive scan
        if (g == 0 && tid == 63) *nclust = x;
    }
    __syncthreads();
    int stride = NBLK_MIS << 9;                   // 8 * 512
    for (int j = (g << 9) + tid; j < n; j += stride) {
        int rb = j >> 6;
        int best = -1;
        u64 tmp = occL[rb];
        while (tmp) {
            int w2 = (int)__ffsll(tmp) - 1; tmp &= tmp - 1;
            u64 m = adjC[(size_t)w2 * n + j] & smS[w2];   // coalesced across j
            if (m) best = (w2 << 6) + 63 - (int)__clzll(m);
        }
        int idx = 0;
        if (best >= 0) {
            int w2 = best >> 6, b = best & 63;
            u64 incl = (b >= 63) ? ~0ull : ((2ull << b) - 1ull);
            idx = wsS[w2] + (int)__popcll(smS[w2] & incl);  // 1-based cid
        }
        indices[j] = idx;
        int bj = j & 63;
        if ((smS[rb] >> bj) & 1ull) {
            int rank = wsS[rb] + (int)__popcll(smS[rb] & (bj ? ((1ull << bj) - 1ull) : 0ull)) + 1;
            seedList[rank - 1] = j;
        }
    }
}

// ---------------- Kernel 3: per-cluster fusion (grid-stride, 1 wave/block) ----
__global__ void fusion_kernel(const float* __restrict__ boxes,
                              const float* __restrict__ scores,
                              const int* __restrict__ indices,
                              const int* __restrict__ seedListG,
                              const int* __restrict__ nclust,
                              const u64* __restrict__ adjC,
                              float* __restrict__ fused,
                              float* __restrict__ sfused,
                              int* __restrict__ validArr, int n, int words) {
    int lane = threadIdx.x;       // 64 = 1 wave
    int nc = *nclust;
    __shared__ unsigned short js[256];
    __shared__ float ms[256];
    __shared__ float ds[256];
    for (int i = blockIdx.x; i < n; i += gridDim.x) {
        int cid = i + 1;
        if (cid > nc) {
            if (lane < 7) fused[i*7+lane] = 0.0f;
            if (lane == 0) { sfused[i] = 0.0f; validArr[i] = 0; }
            continue;
        }
        int s = seedListG[i];
        u64 bits = (lane < words) ? adjC[(size_t)lane * n + s] : 0ull;
        // filter: keep only nodes whose final cluster is cid
        u64 keep = 0ull;
        u64 t = bits;
        while (t) {
            int b = (int)__ffsll(t) - 1;
            t &= t - 1;
            int node = (lane << 6) + b;
            if (indices[node] == cid) keep |= (1ull << b);
        }
        int cnt = __popcll(keep);
        int x = cnt;
        for (int o = 1; o < 64; o <<= 1) {
            int y = __shfl_up(x, o);
            if (lane >= o) x += y;
        }
        int excl = x - cnt;
        int m = __shfl(x, 63);
        int pos = excl;
        t = keep;
        while (t) {
            int b = (int)__ffsll(t) - 1;
            t &= t - 1;
            js[pos++] = (unsigned short)((lane << 6) + b);
        }
        __syncthreads();
        for (int k = lane; k < m; k += 64) {
            int j = js[k];
            ms[k] = scores[j];
            ds[k] = limit_period_f(boxes[j*7+6]);
        }
        __syncthreads();
        if (lane == 0) {
            if (m == 0) {
                for (int k = 0; k < 7; ++k) fused[i*7+k] = 0.0f;
                sfused[i] = 0.0f; validArr[i] = 0;
            } else {
                // s_sum and argmax (first occurrence of max; js ascending + strict >)
                float ssum = 0.0f, smax = -1e30f; int kref = 0;
                for (int k = 0; k < m; ++k) {
                    float sc = ms[k];
                    ssum += sc;
                    if (sc > smax) { smax = sc; kref = k; }
                }
                float refdir = ds[kref];
                float denom = fmaxf(ssum, 1e-12f);
                float sgt = 0.0f;
                float cd0=0,cd1=0,cd2=0,cd3=0,cd4=0,cd5=0;
                for (int k = 0; k < m; ++k) {
                    int j = js[k];
                    float sc = ms[k];
                    float d = fabsf(ds[k] - refdir);
                    if (d > PI_F) d = TWO_PI_F - d;
                    if (d > HALF_PI_F) sgt += sc;
                    float wgt = sc / denom;
                    cd0 += wgt * boxes[j*7+0];
                    cd1 += wgt * boxes[j*7+1];
                    cd2 += wgt * boxes[j*7+2];
                    cd3 += wgt * boxes[j*7+3];
                    cd4 += wgt * boxes[j*7+4];
                    cd5 += wgt * boxes[j*7+5];
                }
                float sle = ssum - sgt;
                bool flipGt = (sgt <= sle);
                float ssin = 0.0f, scos = 0.0f;
                for (int k = 0; k < m; ++k) {
                    float sc = ms[k];
                    float dj = ds[k];
                    float d = fabsf(dj - refdir);
                    if (d > PI_F) d = TWO_PI_F - d;
                    bool gt = d > HALF_PI_F;
                    bool flip = flipGt ? gt : !gt;
                    float adj_d = limit_period_f(dj + (flip ? PI_F : 0.0f));
                    float wgt = sc / denom;
                    ssin += sinf(adj_d) * wgt;
                    scos += cosf(adj_d) * wgt;
                }
                float theta = atan2f(ssin, scos);
                // s_fused: sort member scores descending, sum s_k^(k+1)
                for (int k = 1; k < m; ++k) {
                    float key = ms[k]; int p = k - 1;
                    while (p >= 0 && ms[p] < key) { ms[p+1] = ms[p]; --p; }
                    ms[p+1] = key;
                }
                float sf = 0.0f;
                for (int k = 0; k < m; ++k) sf += powf(ms[k], (float)(k+1));
                sf = fminf(sf, 1.0f);
                // corners range check
                float c_ = cosf(theta), s_ = sinf(theta);
                float wdim = cd4, ldim = cd5;
                const float xs[4]  = {0.5f, 0.5f, -0.5f, -0.5f};
                const float ys_[4] = {-0.5f, 0.5f, 0.5f, -0.5f};
                bool inr = true;
                for (int c = 0; c < 4; ++c) {
                    float cx = ldim * xs[c], cy = wdim * ys_[c];
                    float rx = cx*c_ - cy*s_ + cd0;
                    float ry = cx*s_ + cy*c_ + cd1;
                    inr = inr && (rx > -140.8f) && (rx < 140.8f) && (ry > -40.0f) && (ry < 40.0f);
                }
                fused[i*7+0]=cd0; fused[i*7+1]=cd1; fused[i*7+2]=cd2;
                fused[i*7+3]=cd3; fused[i*7+4]=cd4; fused[i*7+5]=cd5;
                fused[i*7+6]=theta;
                sfused[i] = sf;
                validArr[i] = inr ? 1 : 0;
            }
        }
        __syncthreads();
    }
}

// ---------------- Kernel 4: cumsum + gated output writes ----------------
__global__ void finalize_kernel(const float* __restrict__ fused,
                                const float* __restrict__ sfused,
                                const int* __restrict__ validArr,
                                const int* __restrict__ indices,
                                float* __restrict__ out, int n) {
    __shared__ int newidS[4096];
    __shared__ unsigned char validS[4096];
    __shared__ int scanBuf[1024];
    int tid = threadIdx.x;  // 1024
    int per = (n + 1023) >> 10;  // 4
    int base = tid * per;
    int v[8];
    int sum = 0;
    for (int k = 0; k < per && k < 8; ++k) {
        int j = base + k;
        int vv = (j < n) ? validArr[j] : 0;
        v[k] = vv; sum += vv;
    }
    scanBuf[tid] = sum;
    __syncthreads();
    for (int o = 1; o < 1024; o <<= 1) {
        int val = scanBuf[tid];
        int add = (tid >= o) ? scanBuf[tid - o] : 0;
        __syncthreads();
        scanBuf[tid] = val + add;
        __syncthreads();
    }
    int run = scanBuf[tid] - sum;
    for (int k = 0; k < per && k < 8; ++k) {
        int j = base + k;
        if (j < n) { run += v[k]; newidS[j] = run; validS[j] = (unsigned char)v[k]; }
    }
    __syncthreads();
    float* boxesO  = out;
    float* scoresO = out + (size_t)7*n;
    float* validO  = out + (size_t)8*n;
    float* idxO    = out + (size_t)9*n;
    for (int j = tid; j < n; j += 1024) {
        int vv = validS[j];
        #pragma unroll
        for (int k = 0; k < 7; ++k)
            boxesO[j*7+k] = vv ? fused[j*7+k] : 0.0f;
        scoresO[j] = vv ? sfused[j] : 0.0f;
        validO[j]  = vv ? 1.0f : 0.0f;
        int ind = indices[j];
        int safe = ind - 1; if (safe < 0) safe = 0;
        bool nv = (ind > 0) && (validS[safe] != 0);
        idxO[j] = nv ? (float)newidS[safe] : 0.0f;
    }
}

extern "C" void kernel_launch(void* const* d_in, const int* in_sizes, int n_in,
                              void* d_out, int out_size, void* d_ws, size_t ws_size,
                              hipStream_t stream) {
    const float* boxes  = (const float*)d_in[0];
    const float* scores = (const float*)d_in[1];
    int n = in_sizes[0] / 7;           // 4096
    int words = (n + 63) >> 6;         // 64

    char* ws = (char*)d_ws;
    size_t off = 0;
    u64* adjC = (u64*)(ws + off);
    off += (size_t)n * words * sizeof(u64);
    unsigned char* occByte = (unsigned char*)(ws + off); off += 64 * 64;
    u64* S = (u64*)(ws + off); off += 64 * sizeof(u64);
    u64* R = (u64*)(ws + off); off += 64 * sizeof(u64);
    int* seedList = (int*)(ws + off); off += (size_t)n * sizeof(int);
    int* indices  = (int*)(ws + off); off += (size_t)n * sizeof(int);
    float* fused  = (float*)(ws + off); off += (size_t)n * 7 * sizeof(float);
    float* sfused = (float*)(ws + off); off += (size_t)n * sizeof(float);
    int* validArr = (int*)(ws + off); off += (size_t)n * sizeof(int);
    int* nclust   = (int*)(ws + off); off += sizeof(int);
    off = (off + 7) & ~(size_t)7;
    int* ctrl     = (int*)(ws + off); off += (2 + ROUNDS_MAX) * sizeof(int);

    dim3 adjGrid(words, (n + 255) / 256);
    adj_kernel<<<adjGrid, 256, 0, stream>>>(boxes, adjC, occByte, ctrl, n, words);
    mis_kernel<<<NBLK_MIS, 512, 0, stream>>>(adjC, occByte, S, R, indices, seedList,
                                             nclust, ctrl, n, words);
    fusion_kernel<<<512, 64, 0, stream>>>(boxes, scores, indices, seedList, nclust,
                                          adjC, fused, sfused, validArr, n, words);
    finalize_kernel<<<1, 1024, 0, stream>>>(fused, sfused, validArr, indices,
                                            (float*)d_out, n);
}

// Round 16
// 114.877 us; speedup vs baseline: 1.7937x; 1.7937x over previous
//
#include <hip/hip_runtime.h>
#include <math.h>

#define PI_F      3.141592653f
#define TWO_PI_F  6.283185306f
#define HALF_PI_F 1.5707963265f
#define IOU_THR_F 0.1f

typedef unsigned long long u64;

__device__ __forceinline__ float limit_period_f(float v) {
    return v - floorf(v / TWO_PI_F + 0.5f) * TWO_PI_F;
}

// ---------------- Kernel 1: adjacency + occByte (single-producer, no atomics) -
// Thread owns (row i, word w): 64 in-register IoUs vs LDS-staged j-boxes.
// adjC[(size_t)w * n + i] = word w of row i.
// occByte[rb*64 + w] = 1 iff any row in block rb has nonzero word w.
__global__ void adj_kernel(const float* __restrict__ boxes,
                           u64* __restrict__ adjC,
                           unsigned char* __restrict__ occByte,
                           int n, int words) {
    __shared__ float jS[7][64];
    int w = blockIdx.x;
    int tid = threadIdx.x;              // 256 = 4 waves
    int lane = tid & 63, wv = tid >> 6;
    if (tid < 64) {
        int j = (w << 6) + tid;
        if (j < n) {
            float b0 = boxes[j*7+0], b1 = boxes[j*7+1], b2 = boxes[j*7+2];
            float b3 = boxes[j*7+3], b4 = boxes[j*7+4], b5 = boxes[j*7+5];
            jS[0][tid] = b0 - b5*0.5f;  jS[3][tid] = b0 + b5*0.5f;
            jS[1][tid] = b1 - b4*0.5f;  jS[4][tid] = b1 + b4*0.5f;
            jS[2][tid] = b2 - b3*0.5f;  jS[5][tid] = b2 + b3*0.5f;
            jS[6][tid] = (b5*b4)*b3;
        }
    }
    __syncthreads();
    int i = blockIdx.y * 256 + tid;
    u64 word = 0ull;
    if (i < n) {
        float b0 = boxes[i*7+0], b1 = boxes[i*7+1], b2 = boxes[i*7+2];
        float b3 = boxes[i*7+3], b4 = boxes[i*7+4], b5 = boxes[i*7+5];
        float lix = b0 - b5*0.5f, hix = b0 + b5*0.5f;
        float liy = b1 - b4*0.5f, hiy = b1 + b4*0.5f;
        float liz = b2 - b3*0.5f, hiz = b2 + b3*0.5f;
        float vi  = (b5*b4)*b3;
        int jmax = n - (w << 6); if (jmax > 64) jmax = 64;
        for (int jj = 0; jj < jmax; ++jj) {
            float ix = fminf(hix, jS[3][jj]) - fmaxf(lix, jS[0][jj]); ix = fmaxf(ix, 0.0f);
            float iy = fminf(hiy, jS[4][jj]) - fmaxf(liy, jS[1][jj]); iy = fmaxf(iy, 0.0f);
            float iz = fminf(hiz, jS[5][jj]) - fmaxf(liz, jS[2][jj]); iz = fmaxf(iz, 0.0f);
            float inter = (ix*iy)*iz;
            float u = fmaxf(vi + jS[6][jj] - inter, 1e-8f);
            bool pred = (inter / u) > IOU_THR_F;
            word |= ((u64)(pred ? 1 : 0)) << jj;
        }
        adjC[(size_t)w * n + i] = word;
    }
    u64 bal = __ballot((i < n) && word != 0ull);
    int rb = blockIdx.y * 4 + wv;
    if (lane == 0 && rb < 64)
        occByte[rb * 64 + w] = bal ? (unsigned char)1 : (unsigned char)0;
}

// ---------------- Kernel 2: node-level bit-parallel Jacobi MIS (1 block) ------
// seed(i) <=> no earlier neighbor of i is a seed. Status = two LDS bitsets
// S_l/R_l. Per node per round: ~3 u64 ops per occupied row word. Decisions
// published via wave-aggregated ballots (node bit == lane bit): one LDS
// atomicOr per (wave,k). Two-phase rounds; early-exit on convergence
// (smallest unresolved node always resolves => termination guaranteed).
// Then indices/seedList/nclust fused (reusing per-node nz masks).
__global__ __launch_bounds__(1024) void mis_node_kernel(
        const u64* __restrict__ adjC,
        const unsigned char* __restrict__ occByte,
        int* __restrict__ indices,
        int* __restrict__ seedList,
        int* __restrict__ nclust,
        int n, int words) {
    __shared__ u64 S_l[64], R_l[64], occL[64];
    __shared__ int unresolved;
    __shared__ int wsS[64];
    int tid = threadIdx.x;              // 1024 = 16 waves
    int lane = tid & 63, wv = tid >> 6;

    // occL[rb] = word-occupancy mask of row-block rb (ballot over occByte)
    for (int rb = wv; rb < 64; rb += 16) {
        unsigned char b = occByte[rb * 64 + lane];
        u64 m = __ballot(b != 0);
        if (lane == 0) occL[rb] = m;
    }
    if (tid < 64) {
        int base = tid << 6;
        int vb = n - base;
        u64 valid = (vb >= 64) ? ~0ull : ((vb <= 0) ? 0ull : ((1ull << vb) - 1ull));
        S_l[tid] = 0ull;
        R_l[tid] = ~valid;              // invalid tail = resolved nonseed
    }
    __syncthreads();

    // per-node nonzero-word masks (4 nodes/thread, node i = (k<<10)+tid)
    u64 nzm[4];
    #pragma unroll
    for (int k = 0; k < 4; ++k) {
        int i = (k << 10) + tid;
        u64 nz = 0ull;
        if (i < n) {
            u64 oc = occL[i >> 6];      // wave-uniform list
            while (oc) {
                int e = (int)__ffsll(oc) - 1; oc &= oc - 1;
                if (e < words && adjC[(size_t)e * n + i] != 0ull) nz |= 1ull << e;
            }
        }
        nzm[k] = nz;
    }

    unsigned done = 0;
    #pragma unroll
    for (int k = 0; k < 4; ++k)
        if (((k << 10) + tid) >= n) done |= 1u << k;

    for (;;) {
        if (tid == 0) unresolved = 0;
        unsigned pendSeed = 0, pendRes = 0;
        // ---- read phase (no writes to S_l/R_l) ----
        #pragma unroll
        for (int k = 0; k < 4; ++k) {
            if (done & (1u << k)) continue;
            int i = (k << 10) + tid;
            int w_i = i >> 6, b_i = i & 63;
            u64 sA = 0ull, uA = 0ull;
            u64 m = nzm[k];
            while (m) {
                int e = (int)__ffsll(m) - 1; m &= m - 1;
                if (e > w_i) break;     // later words: no earlier neighbors
                u64 row = adjC[(size_t)e * n + i];
                u64 em = (e < w_i) ? ~0ull : (b_i ? ((1ull << b_i) - 1ull) : 0ull);
                sA |= row & S_l[e] & em;
                uA |= row & ~R_l[e] & em;
            }
            if (sA) pendRes |= 1u << k;                       // nonseed
            else if (!uA) { pendSeed |= 1u << k; pendRes |= 1u << k; }  // seed
        }
        __syncthreads();
        // ---- write phase: wave-aggregated (i&63 == lane) ----
        #pragma unroll
        for (int k = 0; k < 4; ++k) {
            u64 bS = __ballot((pendSeed >> k) & 1u);
            u64 bR = __ballot((pendRes  >> k) & 1u);
            int w_i = ((k << 10) + tid) >> 6;                 // wave-uniform
            if (lane == 0 && w_i < 64) {
                if (bS) atomicOr(&S_l[w_i], bS);
                if (bR) atomicOr(&R_l[w_i], bR);
            }
        }
        done |= pendRes;
        if ((done & 0xFu) != 0xFu) unresolved = 1;            // benign race
        __syncthreads();
        if (unresolved == 0) break;
    }

    // seed-rank exclusive scan + nclust
    if (tid < 64) {
        int pc = (int)__popcll(S_l[tid]);
        int x = pc;
        for (int o = 1; o < 64; o <<= 1) {
            int y = __shfl_up(x, o);
            if (tid >= o) x += y;
        }
        wsS[tid] = x - pc;
        if (tid == 63) *nclust = x;
    }
    __syncthreads();
    // indices[j] = rank of max-index adjacent seed; seedList
    #pragma unroll
    for (int k = 0; k < 4; ++k) {
        int i = (k << 10) + tid;
        if (i >= n) continue;
        int best = -1;
        u64 m = nzm[k];
        while (m) {
            int e = (int)__ffsll(m) - 1; m &= m - 1;
            u64 s = adjC[(size_t)e * n + i] & S_l[e];
            if (s) best = (e << 6) + 63 - (int)__clzll(s);
        }
        int idx = 0;
        if (best >= 0) {
            int w2 = best >> 6, b = best & 63;
            u64 incl = (b >= 63) ? ~0ull : ((2ull << b) - 1ull);
            idx = wsS[w2] + (int)__popcll(S_l[w2] & incl);    // 1-based cid
        }
        indices[i] = idx;
        int wj = i >> 6, bj = i & 63;
        if ((S_l[wj] >> bj) & 1ull) {
            int rank = wsS[wj] + (int)__popcll(S_l[wj] & (bj ? ((1ull << bj) - 1ull) : 0ull)) + 1;
            seedList[rank - 1] = i;
        }
    }
}

// ---------------- Kernel 3: per-cluster fusion (grid-stride, 1 wave/block) ----
__global__ void fusion_kernel(const float* __restrict__ boxes,
                              const float* __restrict__ scores,
                              const int* __restrict__ indices,
                              const int* __restrict__ seedListG,
                              const int* __restrict__ nclust,
                              const u64* __restrict__ adjC,
                              float* __restrict__ fused,
                              float* __restrict__ sfused,
                              int* __restrict__ validArr, int n, int words) {
    int lane = threadIdx.x;       // 64 = 1 wave
    int nc = *nclust;
    __shared__ unsigned short js[256];
    __shared__ float ms[256];
    __shared__ float ds[256];
    for (int i = blockIdx.x; i < n; i += gridDim.x) {
        int cid = i + 1;
        if (cid > nc) {
            if (lane < 7) fused[i*7+lane] = 0.0f;
            if (lane == 0) { sfused[i] = 0.0f; validArr[i] = 0; }
            continue;
        }
        int s = seedListG[i];
        u64 bits = (lane < words) ? adjC[(size_t)lane * n + s] : 0ull;
        // filter: keep only nodes whose final cluster is cid
        u64 keep = 0ull;
        u64 t = bits;
        while (t) {
            int b = (int)__ffsll(t) - 1;
            t &= t - 1;
            int node = (lane << 6) + b;
            if (indices[node] == cid) keep |= (1ull << b);
        }
        int cnt = __popcll(keep);
        int x = cnt;
        for (int o = 1; o < 64; o <<= 1) {
            int y = __shfl_up(x, o);
            if (lane >= o) x += y;
        }
        int excl = x - cnt;
        int m = __shfl(x, 63);
        int pos = excl;
        t = keep;
        while (t) {
            int b = (int)__ffsll(t) - 1;
            t &= t - 1;
            js[pos++] = (unsigned short)((lane << 6) + b);
        }
        __syncthreads();
        for (int k = lane; k < m; k += 64) {
            int j = js[k];
            ms[k] = scores[j];
            ds[k] = limit_period_f(boxes[j*7+6]);
        }
        __syncthreads();
        if (lane == 0) {
            if (m == 0) {
                for (int k = 0; k < 7; ++k) fused[i*7+k] = 0.0f;
                sfused[i] = 0.0f; validArr[i] = 0;
            } else {
                // s_sum and argmax (first occurrence of max; js ascending + strict >)
                float ssum = 0.0f, smax = -1e30f; int kref = 0;
                for (int k = 0; k < m; ++k) {
                    float sc = ms[k];
                    ssum += sc;
                    if (sc > smax) { smax = sc; kref = k; }
                }
                float refdir = ds[kref];
                float denom = fmaxf(ssum, 1e-12f);
                float sgt = 0.0f;
                float cd0=0,cd1=0,cd2=0,cd3=0,cd4=0,cd5=0;
                for (int k = 0; k < m; ++k) {
                    int j = js[k];
                    float sc = ms[k];
                    float d = fabsf(ds[k] - refdir);
                    if (d > PI_F) d = TWO_PI_F - d;
                    if (d > HALF_PI_F) sgt += sc;
                    float wgt = sc / denom;
                    cd0 += wgt * boxes[j*7+0];
                    cd1 += wgt * boxes[j*7+1];
                    cd2 += wgt * boxes[j*7+2];
                    cd3 += wgt * boxes[j*7+3];
                    cd4 += wgt * boxes[j*7+4];
                    cd5 += wgt * boxes[j*7+5];
                }
                float sle = ssum - sgt;
                bool flipGt = (sgt <= sle);
                float ssin = 0.0f, scos = 0.0f;
                for (int k = 0; k < m; ++k) {
                    float sc = ms[k];
                    float dj = ds[k];
                    float d = fabsf(dj - refdir);
                    if (d > PI_F) d = TWO_PI_F - d;
                    bool gt = d > HALF_PI_F;
                    bool flip = flipGt ? gt : !gt;
                    float adj_d = limit_period_f(dj + (flip ? PI_F : 0.0f));
                    float wgt = sc / denom;
                    ssin += sinf(adj_d) * wgt;
                    scos += cosf(adj_d) * wgt;
                }
                float theta = atan2f(ssin, scos);
                // s_fused: sort member scores descending, sum s_k^(k+1)
                for (int k = 1; k < m; ++k) {
                    float key = ms[k]; int p = k - 1;
                    while (p >= 0 && ms[p] < key) { ms[p+1] = ms[p]; --p; }
                    ms[p+1] = key;
                }
                float sf = 0.0f;
                for (int k = 0; k < m; ++k) sf += powf(ms[k], (float)(k+1));
                sf = fminf(sf, 1.0f);
                // corners range check
                float c_ = cosf(theta), s_ = sinf(theta);
                float wdim = cd4, ldim = cd5;
                const float xs[4]  = {0.5f, 0.5f, -0.5f, -0.5f};
                const float ys_[4] = {-0.5f, 0.5f, 0.5f, -0.5f};
                bool inr = true;
                for (int c = 0; c < 4; ++c) {
                    float cx = ldim * xs[c], cy = wdim * ys_[c];
                    float rx = cx*c_ - cy*s_ + cd0;
                    float ry = cx*s_ + cy*c_ + cd1;
                    inr = inr && (rx > -140.8f) && (rx < 140.8f) && (ry > -40.0f) && (ry < 40.0f);
                }
                fused[i*7+0]=cd0; fused[i*7+1]=cd1; fused[i*7+2]=cd2;
                fused[i*7+3]=cd3; fused[i*7+4]=cd4; fused[i*7+5]=cd5;
                fused[i*7+6]=theta;
                sfused[i] = sf;
                validArr[i] = inr ? 1 : 0;
            }
        }
        __syncthreads();
    }
}

// ---------------- Kernel 4: cumsum + gated output writes ----------------
__global__ void finalize_kernel(const float* __restrict__ fused,
                                const float* __restrict__ sfused,
                                const int* __restrict__ validArr,
                                const int* __restrict__ indices,
                                float* __restrict__ out, int n) {
    __shared__ int newidS[4096];
    __shared__ unsigned char validS[4096];
    __shared__ int scanBuf[1024];
    int tid = threadIdx.x;  // 1024
    int per = (n + 1023) >> 10;  // 4
    int base = tid * per;
    int v[8];
    int sum = 0;
    for (int k = 0; k < per && k < 8; ++k) {
        int j = base + k;
        int vv = (j < n) ? validArr[j] : 0;
        v[k] = vv; sum += vv;
    }
    scanBuf[tid] = sum;
    __syncthreads();
    for (int o = 1; o < 1024; o <<= 1) {
        int val = scanBuf[tid];
        int add = (tid >= o) ? scanBuf[tid - o] : 0;
        __syncthreads();
        scanBuf[tid] = val + add;
        __syncthreads();
    }
    int run = scanBuf[tid] - sum;
    for (int k = 0; k < per && k < 8; ++k) {
        int j = base + k;
        if (j < n) { run += v[k]; newidS[j] = run; validS[j] = (unsigned char)v[k]; }
    }
    __syncthreads();
    float* boxesO  = out;
    float* scoresO = out + (size_t)7*n;
    float* validO  = out + (size_t)8*n;
    float* idxO    = out + (size_t)9*n;
    for (int j = tid; j < n; j += 1024) {
        int vv = validS[j];
        #pragma unroll
        for (int k = 0; k < 7; ++k)
            boxesO[j*7+k] = vv ? fused[j*7+k] : 0.0f;
        scoresO[j] = vv ? sfused[j] : 0.0f;
        validO[j]  = vv ? 1.0f : 0.0f;
        int ind = indices[j];
        int safe = ind - 1; if (safe < 0) safe = 0;
        bool nv = (ind > 0) && (validS[safe] != 0);
        idxO[j] = nv ? (float)newidS[safe] : 0.0f;
    }
}

extern "C" void kernel_launch(void* const* d_in, const int* in_sizes, int n_in,
                              void* d_out, int out_size, void* d_ws, size_t ws_size,
                              hipStream_t stream) {
    const float* boxes  = (const float*)d_in[0];
    const float* scores = (const float*)d_in[1];
    int n = in_sizes[0] / 7;           // 4096
    int words = (n + 63) >> 6;         // 64

    char* ws = (char*)d_ws;
    size_t off = 0;
    u64* adjC = (u64*)(ws + off);
    off += (size_t)n * words * sizeof(u64);
    unsigned char* occByte = (unsigned char*)(ws + off); off += 64 * 64;
    int* seedList = (int*)(ws + off); off += (size_t)n * sizeof(int);
    int* indices  = (int*)(ws + off); off += (size_t)n * sizeof(int);
    float* fused  = (float*)(ws + off); off += (size_t)n * 7 * sizeof(float);
    float* sfused = (float*)(ws + off); off += (size_t)n * sizeof(float);
    int* validArr = (int*)(ws + off); off += (size_t)n * sizeof(int);
    int* nclust   = (int*)(ws + off); off += sizeof(int);

    dim3 adjGrid(words, (n + 255) / 256);
    adj_kernel<<<adjGrid, 256, 0, stream>>>(boxes, adjC, occByte, n, words);
    mis_node_kernel<<<1, 1024, 0, stream>>>(adjC, occByte, indices, seedList,
                                            nclust, n, words);
    fusion_kernel<<<512, 64, 0, stream>>>(boxes, scores, indices, seedList, nclust,
                                          adjC, fused, sfused, validArr, n, words);
    finalize_kernel<<<1, 1024, 0, stream>>>(fused, sfused, validArr, indices,
                                            (float*)d_out, n);
}

// Round 17
// 94.511 us; speedup vs baseline: 2.1802x; 1.2155x over previous
//
#include <hip/hip_runtime.h>
#include <math.h>

#define PI_F      3.141592653f
#define TWO_PI_F  6.283185306f
#define HALF_PI_F 1.5707963265f
#define IOU_THR_F 0.1f

typedef unsigned long long u64;

__device__ __forceinline__ float limit_period_f(float v) {
    return v - floorf(v / TWO_PI_F + 0.5f) * TWO_PI_F;
}

// ---------------- Kernel 1: adjacency + occByte (single-producer, no atomics) -
// Thread owns (row i, word w): 64 in-register IoUs vs LDS-staged j-boxes.
// adjC[(size_t)w * n + i] = word w of row i.
// occByte[rb*64 + w] = 1 iff any row in block rb has nonzero word w.
__global__ void adj_kernel(const float* __restrict__ boxes,
                           u64* __restrict__ adjC,
                           unsigned char* __restrict__ occByte,
                           int n, int words) {
    __shared__ float jS[7][64];
    int w = blockIdx.x;
    int tid = threadIdx.x;              // 256 = 4 waves
    int lane = tid & 63, wv = tid >> 6;
    if (tid < 64) {
        int j = (w << 6) + tid;
        if (j < n) {
            float b0 = boxes[j*7+0], b1 = boxes[j*7+1], b2 = boxes[j*7+2];
            float b3 = boxes[j*7+3], b4 = boxes[j*7+4], b5 = boxes[j*7+5];
            jS[0][tid] = b0 - b5*0.5f;  jS[3][tid] = b0 + b5*0.5f;
            jS[1][tid] = b1 - b4*0.5f;  jS[4][tid] = b1 + b4*0.5f;
            jS[2][tid] = b2 - b3*0.5f;  jS[5][tid] = b2 + b3*0.5f;
            jS[6][tid] = (b5*b4)*b3;
        }
    }
    __syncthreads();
    int i = blockIdx.y * 256 + tid;
    u64 word = 0ull;
    if (i < n) {
        float b0 = boxes[i*7+0], b1 = boxes[i*7+1], b2 = boxes[i*7+2];
        float b3 = boxes[i*7+3], b4 = boxes[i*7+4], b5 = boxes[i*7+5];
        float lix = b0 - b5*0.5f, hix = b0 + b5*0.5f;
        float liy = b1 - b4*0.5f, hiy = b1 + b4*0.5f;
        float liz = b2 - b3*0.5f, hiz = b2 + b3*0.5f;
        float vi  = (b5*b4)*b3;
        int jmax = n - (w << 6); if (jmax > 64) jmax = 64;
        for (int jj = 0; jj < jmax; ++jj) {
            float ix = fminf(hix, jS[3][jj]) - fmaxf(lix, jS[0][jj]); ix = fmaxf(ix, 0.0f);
            float iy = fminf(hiy, jS[4][jj]) - fmaxf(liy, jS[1][jj]); iy = fmaxf(iy, 0.0f);
            float iz = fminf(hiz, jS[5][jj]) - fmaxf(liz, jS[2][jj]); iz = fmaxf(iz, 0.0f);
            float inter = (ix*iy)*iz;
            float u = fmaxf(vi + jS[6][jj] - inter, 1e-8f);
            bool pred = (inter / u) > IOU_THR_F;
            word |= ((u64)(pred ? 1 : 0)) << jj;
        }
        adjC[(size_t)w * n + i] = word;
    }
    u64 bal = __ballot((i < n) && word != 0ull);
    int rb = blockIdx.y * 4 + wv;
    if (lane == 0 && rb < 64)
        occByte[rb * 64 + w] = bal ? (unsigned char)1 : (unsigned char)0;
}

// ---------------- Kernel 2: node-level bit-parallel Jacobi MIS (1 block) ------
// (R16-validated) seed(i) <=> no earlier neighbor of i is a seed.
__global__ __launch_bounds__(1024) void mis_node_kernel(
        const u64* __restrict__ adjC,
        const unsigned char* __restrict__ occByte,
        int* __restrict__ indices,
        int* __restrict__ seedList,
        int* __restrict__ nclust,
        int n, int words) {
    __shared__ u64 S_l[64], R_l[64], occL[64];
    __shared__ int unresolved;
    __shared__ int wsS[64];
    int tid = threadIdx.x;              // 1024 = 16 waves
    int lane = tid & 63, wv = tid >> 6;

    for (int rb = wv; rb < 64; rb += 16) {
        unsigned char b = occByte[rb * 64 + lane];
        u64 m = __ballot(b != 0);
        if (lane == 0) occL[rb] = m;
    }
    if (tid < 64) {
        int base = tid << 6;
        int vb = n - base;
        u64 valid = (vb >= 64) ? ~0ull : ((vb <= 0) ? 0ull : ((1ull << vb) - 1ull));
        S_l[tid] = 0ull;
        R_l[tid] = ~valid;              // invalid tail = resolved nonseed
    }
    __syncthreads();

    u64 nzm[4];
    #pragma unroll
    for (int k = 0; k < 4; ++k) {
        int i = (k << 10) + tid;
        u64 nz = 0ull;
        if (i < n) {
            u64 oc = occL[i >> 6];
            while (oc) {
                int e = (int)__ffsll(oc) - 1; oc &= oc - 1;
                if (e < words && adjC[(size_t)e * n + i] != 0ull) nz |= 1ull << e;
            }
        }
        nzm[k] = nz;
    }

    unsigned done = 0;
    #pragma unroll
    for (int k = 0; k < 4; ++k)
        if (((k << 10) + tid) >= n) done |= 1u << k;

    for (;;) {
        if (tid == 0) unresolved = 0;
        unsigned pendSeed = 0, pendRes = 0;
        #pragma unroll
        for (int k = 0; k < 4; ++k) {
            if (done & (1u << k)) continue;
            int i = (k << 10) + tid;
            int w_i = i >> 6, b_i = i & 63;
            u64 sA = 0ull, uA = 0ull;
            u64 m = nzm[k];
            while (m) {
                int e = (int)__ffsll(m) - 1; m &= m - 1;
                if (e > w_i) break;
                u64 row = adjC[(size_t)e * n + i];
                u64 em = (e < w_i) ? ~0ull : (b_i ? ((1ull << b_i) - 1ull) : 0ull);
                sA |= row & S_l[e] & em;
                uA |= row & ~R_l[e] & em;
            }
            if (sA) pendRes |= 1u << k;
            else if (!uA) { pendSeed |= 1u << k; pendRes |= 1u << k; }
        }
        __syncthreads();
        #pragma unroll
        for (int k = 0; k < 4; ++k) {
            u64 bS = __ballot((pendSeed >> k) & 1u);
            u64 bR = __ballot((pendRes  >> k) & 1u);
            int w_i = ((k << 10) + tid) >> 6;
            if (lane == 0 && w_i < 64) {
                if (bS) atomicOr(&S_l[w_i], bS);
                if (bR) atomicOr(&R_l[w_i], bR);
            }
        }
        done |= pendRes;
        if ((done & 0xFu) != 0xFu) unresolved = 1;
        __syncthreads();
        if (unresolved == 0) break;
    }

    if (tid < 64) {
        int pc = (int)__popcll(S_l[tid]);
        int x = pc;
        for (int o = 1; o < 64; o <<= 1) {
            int y = __shfl_up(x, o);
            if (tid >= o) x += y;
        }
        wsS[tid] = x - pc;
        if (tid == 63) *nclust = x;
    }
    __syncthreads();
    #pragma unroll
    for (int k = 0; k < 4; ++k) {
        int i = (k << 10) + tid;
        if (i >= n) continue;
        int best = -1;
        u64 m = nzm[k];
        while (m) {
            int e = (int)__ffsll(m) - 1; m &= m - 1;
            u64 s = adjC[(size_t)e * n + i] & S_l[e];
            if (s) best = (e << 6) + 63 - (int)__clzll(s);
        }
        int idx = 0;
        if (best >= 0) {
            int w2 = best >> 6, b = best & 63;
            u64 incl = (b >= 63) ? ~0ull : ((2ull << b) - 1ull);
            idx = wsS[w2] + (int)__popcll(S_l[w2] & incl);
        }
        indices[i] = idx;
        int wj = i >> 6, bj = i & 63;
        if ((S_l[wj] >> bj) & 1ull) {
            int rank = wsS[wj] + (int)__popcll(S_l[wj] & (bj ? ((1ull << bj) - 1ull) : 0ull)) + 1;
            seedList[rank - 1] = i;
        }
    }
}

// ---------------- Kernel 3: per-cluster fusion (LDS-staged, phase-split) ------
// All member data staged to LDS by 64 lanes; lane-0 serial math touches only
// LDS (identical arithmetic order => bit-identical). Transcendentals computed
// per-element in parallel (phase B), summed serially in the same order.
__global__ void fusion_kernel(const float* __restrict__ boxes,
                              const float* __restrict__ scores,
                              const int* __restrict__ indices,
                              const int* __restrict__ seedListG,
                              const int* __restrict__ nclust,
                              const u64* __restrict__ adjC,
                              float* __restrict__ fused,
                              float* __restrict__ sfused,
                              int* __restrict__ validArr, int n, int words) {
    int lane = threadIdx.x;       // 64 = 1 wave
    int nc = *nclust;
    __shared__ unsigned short js[256];
    __shared__ float ms[256];
    __shared__ float ds[256];
    __shared__ float bx[6][256];
    __shared__ float sv[256], cv[256], pw[256];
    __shared__ float refdirS, denomS;
    __shared__ int   flipS, mS;
    for (int i = blockIdx.x; i < n; i += gridDim.x) {
        int cid = i + 1;
        if (cid > nc) {
            if (lane < 7) fused[i*7+lane] = 0.0f;
            if (lane == 0) { sfused[i] = 0.0f; validArr[i] = 0; }
            continue;
        }
        int s = seedListG[i];
        u64 bits = (lane < words) ? adjC[(size_t)lane * n + s] : 0ull;
        // filter: keep only nodes whose final cluster is cid
        u64 keep = 0ull;
        u64 t = bits;
        while (t) {
            int b = (int)__ffsll(t) - 1;
            t &= t - 1;
            int node = (lane << 6) + b;
            if (indices[node] == cid) keep |= (1ull << b);
        }
        int cnt = __popcll(keep);
        int x = cnt;
        for (int o = 1; o < 64; o <<= 1) {
            int y = __shfl_up(x, o);
            if (lane >= o) x += y;
        }
        int excl = x - cnt;
        int m = __shfl(x, 63);
        int pos = excl;
        t = keep;
        while (t) {
            int b = (int)__ffsll(t) - 1;
            t &= t - 1;
            js[pos++] = (unsigned short)((lane << 6) + b);
        }
        __syncthreads();
        // stage ALL member data to LDS (parallel scattered loads)
        for (int k = lane; k < m; k += 64) {
            int j = js[k];
            ms[k] = scores[j];
            ds[k] = limit_period_f(boxes[j*7+6]);
            bx[0][k] = boxes[j*7+0];
            bx[1][k] = boxes[j*7+1];
            bx[2][k] = boxes[j*7+2];
            bx[3][k] = boxes[j*7+3];
            bx[4][k] = boxes[j*7+4];
            bx[5][k] = boxes[j*7+5];
        }
        __syncthreads();
        if (m == 0) {
            if (lane == 0) {
                for (int k = 0; k < 7; ++k) fused[i*7+k] = 0.0f;
                sfused[i] = 0.0f; validArr[i] = 0;
            }
            __syncthreads();
            continue;
        }
        // ---- phase A (lane 0, LDS-only): ssum/argmax/refdir/denom/flip ----
        if (lane == 0) {
            float ssum = 0.0f, smax = -1e30f; int kref = 0;
            for (int k = 0; k < m; ++k) {
                float sc = ms[k];
                ssum += sc;
                if (sc > smax) { smax = sc; kref = k; }
            }
            float refdir = ds[kref];
            float denom = fmaxf(ssum, 1e-12f);
            float sgt = 0.0f;
            for (int k = 0; k < m; ++k) {
                float d = fabsf(ds[k] - refdir);
                if (d > PI_F) d = TWO_PI_F - d;
                if (d > HALF_PI_F) sgt += ms[k];
            }
            float sle = ssum - sgt;
            refdirS = refdir; denomS = denom;
            flipS = (sgt <= sle) ? 1 : 0;
        }
        __syncthreads();
        // ---- phase B (parallel): per-element trig ----
        {
            float refdir = refdirS, denom = denomS;
            bool flipGt = flipS != 0;
            for (int k = lane; k < m; k += 64) {
                float dj = ds[k];
                float d = fabsf(dj - refdir);
                if (d > PI_F) d = TWO_PI_F - d;
                bool gt = d > HALF_PI_F;
                bool flip = flipGt ? gt : !gt;
                float adj_d = limit_period_f(dj + (flip ? PI_F : 0.0f));
                float wgt = ms[k] / denom;
                sv[k] = sinf(adj_d) * wgt;
                cv[k] = cosf(adj_d) * wgt;
            }
        }
        __syncthreads();
        // ---- phase C (lane 0): weighted sums + theta + sort ----
        if (lane == 0) {
            float refdir = refdirS, denom = denomS;
            float sgt_dummy = 0.0f; (void)sgt_dummy; (void)refdir;
            float cd0=0,cd1=0,cd2=0,cd3=0,cd4=0,cd5=0;
            for (int k = 0; k < m; ++k) {
                float wgt = ms[k] / denom;
                cd0 += wgt * bx[0][k];
                cd1 += wgt * bx[1][k];
                cd2 += wgt * bx[2][k];
                cd3 += wgt * bx[3][k];
                cd4 += wgt * bx[4][k];
                cd5 += wgt * bx[5][k];
            }
            float ssin = 0.0f, scos = 0.0f;
            for (int k = 0; k < m; ++k) { ssin += sv[k]; scos += cv[k]; }
            float theta = atan2f(ssin, scos);
            // sort member scores descending (serial, LDS)
            for (int k = 1; k < m; ++k) {
                float key = ms[k]; int p = k - 1;
                while (p >= 0 && ms[p] < key) { ms[p+1] = ms[p]; --p; }
                ms[p+1] = key;
            }
            // stash partial results for final phase
            bx[0][255] = cd0; bx[1][255] = cd1; bx[2][255] = cd2;
            bx[3][255] = cd3; bx[4][255] = cd4; bx[5][255] = cd5;
            sv[255] = theta;
            mS = m;
        }
        __syncthreads();
        // ---- phase D (parallel): powf on sorted scores ----
        for (int k = lane; k < m; k += 64)
            pw[k] = powf(ms[k], (float)(k+1));
        __syncthreads();
        // ---- phase E (lane 0): s_fused + corners + writes ----
        if (lane == 0) {
            float cd0 = bx[0][255], cd1 = bx[1][255], cd2 = bx[2][255];
            float cd3 = bx[3][255], cd4 = bx[4][255], cd5 = bx[5][255];
            float theta = sv[255];
            float sf = 0.0f;
            for (int k = 0; k < m; ++k) sf += pw[k];
            sf = fminf(sf, 1.0f);
            float c_ = cosf(theta), s_ = sinf(theta);
            float wdim = cd4, ldim = cd5;
            const float xs[4]  = {0.5f, 0.5f, -0.5f, -0.5f};
            const float ys_[4] = {-0.5f, 0.5f, 0.5f, -0.5f};
            bool inr = true;
            for (int c = 0; c < 4; ++c) {
                float cx = ldim * xs[c], cy = wdim * ys_[c];
                float rx = cx*c_ - cy*s_ + cd0;
                float ry = cx*s_ + cy*c_ + cd1;
                inr = inr && (rx > -140.8f) && (rx < 140.8f) && (ry > -40.0f) && (ry < 40.0f);
            }
            fused[i*7+0]=cd0; fused[i*7+1]=cd1; fused[i*7+2]=cd2;
            fused[i*7+3]=cd3; fused[i*7+4]=cd4; fused[i*7+5]=cd5;
            fused[i*7+6]=theta;
            sfused[i] = sf;
            validArr[i] = inr ? 1 : 0;
        }
        __syncthreads();
    }
}

// ---------------- Kernel 4: cumsum + gated output writes ----------------
__global__ void finalize_kernel(const float* __restrict__ fused,
                                const float* __restrict__ sfused,
                                const int* __restrict__ validArr,
                                const int* __restrict__ indices,
                                float* __restrict__ out, int n) {
    __shared__ int newidS[4096];
    __shared__ unsigned char validS[4096];
    __shared__ int scanBuf[1024];
    int tid = threadIdx.x;  // 1024
    int per = (n + 1023) >> 10;  // 4
    int base = tid * per;
    int v[8];
    int sum = 0;
    for (int k = 0; k < per && k < 8; ++k) {
        int j = base + k;
        int vv = (j < n) ? validArr[j] : 0;
        v[k] = vv; sum += vv;
    }
    scanBuf[tid] = sum;
    __syncthreads();
    for (int o = 1; o < 1024; o <<= 1) {
        int val = scanBuf[tid];
        int add = (tid >= o) ? scanBuf[tid - o] : 0;
        __syncthreads();
        scanBuf[tid] = val + add;
        __syncthreads();
    }
    int run = scanBuf[tid] - sum;
    for (int k = 0; k < per && k < 8; ++k) {
        int j = base + k;
        if (j < n) { run += v[k]; newidS[j] = run; validS[j] = (unsigned char)v[k]; }
    }
    __syncthreads();
    float* boxesO  = out;
    float* scoresO = out + (size_t)7*n;
    float* validO  = out + (size_t)8*n;
    float* idxO    = out + (size_t)9*n;
    for (int j = tid; j < n; j += 1024) {
        int vv = validS[j];
        #pragma unroll
        for (int k = 0; k < 7; ++k)
            boxesO[j*7+k] = vv ? fused[j*7+k] : 0.0f;
        scoresO[j] = vv ? sfused[j] : 0.0f;
        validO[j]  = vv ? 1.0f : 0.0f;
        int ind = indices[j];
        int safe = ind - 1; if (safe < 0) safe = 0;
        bool nv = (ind > 0) && (validS[safe] != 0);
        idxO[j] = nv ? (float)newidS[safe] : 0.0f;
    }
}

extern "C" void kernel_launch(void* const* d_in, const int* in_sizes, int n_in,
                              void* d_out, int out_size, void* d_ws, size_t ws_size,
                              hipStream_t stream) {
    const float* boxes  = (const float*)d_in[0];
    const float* scores = (const float*)d_in[1];
    int n = in_sizes[0] / 7;           // 4096
    int words = (n + 63) >> 6;         // 64

    char* ws = (char*)d_ws;
    size_t off = 0;
    u64* adjC = (u64*)(ws + off);
    off += (size_t)n * words * sizeof(u64);
    unsigned char* occByte = (unsigned char*)(ws + off); off += 64 * 64;
    int* seedList = (int*)(ws + off); off += (size_t)n * sizeof(int);
    int* indices  = (int*)(ws + off); off += (size_t)n * sizeof(int);
    float* fused  = (float*)(ws + off); off += (size_t)n * 7 * sizeof(float);
    float* sfused = (float*)(ws + off); off += (size_t)n * sizeof(float);
    int* validArr = (int*)(ws + off); off += (size_t)n * sizeof(int);
    int* nclust   = (int*)(ws + off); off += sizeof(int);

    dim3 adjGrid(words, (n + 255) / 256);
    adj_kernel<<<adjGrid, 256, 0, stream>>>(boxes, adjC, occByte, n, words);
    mis_node_kernel<<<1, 1024, 0, stream>>>(adjC, occByte, indices, seedList,
                                            nclust, n, words);
    fusion_kernel<<<512, 64, 0, stream>>>(boxes, scores, indices, seedList, nclust,
                                          adjC, fused, sfused, validArr, n, words);
    finalize_kernel<<<1, 1024, 0, stream>>>(fused, sfused, validArr, indices,
                                            (float*)d_out, n);
}

// Round 18
// 92.920 us; speedup vs baseline: 2.2175x; 1.0171x over previous
//
#include <hip/hip_runtime.h>
#include <math.h>

#define PI_F      3.141592653f
#define TWO_PI_F  6.283185306f
#define HALF_PI_F 1.5707963265f
#define IOU_THR_F 0.1f

typedef unsigned long long u64;

__device__ __forceinline__ float limit_period_f(float v) {
    return v - floorf(v / TWO_PI_F + 0.5f) * TWO_PI_F;
}

// ---------------- Kernel 1: adjacency + occByte (single-producer, no atomics) -
// Thread owns (row i, word w): 64 in-register IoUs vs LDS-staged j-boxes.
// adjC[(size_t)w * n + i] = word w of row i.
// occByte[rb*64 + w] = 1 iff any row in block rb has nonzero word w.
__global__ void adj_kernel(const float* __restrict__ boxes,
                           u64* __restrict__ adjC,
                           unsigned char* __restrict__ occByte,
                           int n, int words) {
    __shared__ float jS[7][64];
    int w = blockIdx.x;
    int tid = threadIdx.x;              // 256 = 4 waves
    int lane = tid & 63, wv = tid >> 6;
    if (tid < 64) {
        int j = (w << 6) + tid;
        if (j < n) {
            float b0 = boxes[j*7+0], b1 = boxes[j*7+1], b2 = boxes[j*7+2];
            float b3 = boxes[j*7+3], b4 = boxes[j*7+4], b5 = boxes[j*7+5];
            jS[0][tid] = b0 - b5*0.5f;  jS[3][tid] = b0 + b5*0.5f;
            jS[1][tid] = b1 - b4*0.5f;  jS[4][tid] = b1 + b4*0.5f;
            jS[2][tid] = b2 - b3*0.5f;  jS[5][tid] = b2 + b3*0.5f;
            jS[6][tid] = (b5*b4)*b3;
        }
    }
    __syncthreads();
    int i = blockIdx.y * 256 + tid;
    u64 word = 0ull;
    if (i < n) {
        float b0 = boxes[i*7+0], b1 = boxes[i*7+1], b2 = boxes[i*7+2];
        float b3 = boxes[i*7+3], b4 = boxes[i*7+4], b5 = boxes[i*7+5];
        float lix = b0 - b5*0.5f, hix = b0 + b5*0.5f;
        float liy = b1 - b4*0.5f, hiy = b1 + b4*0.5f;
        float liz = b2 - b3*0.5f, hiz = b2 + b3*0.5f;
        float vi  = (b5*b4)*b3;
        int jmax = n - (w << 6); if (jmax > 64) jmax = 64;
        for (int jj = 0; jj < jmax; ++jj) {
            float ix = fminf(hix, jS[3][jj]) - fmaxf(lix, jS[0][jj]); ix = fmaxf(ix, 0.0f);
            float iy = fminf(hiy, jS[4][jj]) - fmaxf(liy, jS[1][jj]); iy = fmaxf(iy, 0.0f);
            float iz = fminf(hiz, jS[5][jj]) - fmaxf(liz, jS[2][jj]); iz = fmaxf(iz, 0.0f);
            float inter = (ix*iy)*iz;
            float u = fmaxf(vi + jS[6][jj] - inter, 1e-8f);
            bool pred = (inter / u) > IOU_THR_F;
            word |= ((u64)(pred ? 1 : 0)) << jj;
        }
        adjC[(size_t)w * n + i] = word;
    }
    u64 bal = __ballot((i < n) && word != 0ull);
    int rb = blockIdx.y * 4 + wv;
    if (lane == 0 && rb < 64)
        occByte[rb * 64 + w] = bal ? (unsigned char)1 : (unsigned char)0;
}

// ---------------- Kernel 2: node-level bit-parallel Jacobi MIS (1 block) ------
// (R16-validated logic.) seed(i) <=> no earlier neighbor of i is a seed.
// NEW: earlier-masked rows cached in registers during the build pass; Jacobi
// rounds touch only LDS bitsets + ALU (no global re-reads on the round path).
__global__ __launch_bounds__(1024) void mis_node_kernel(
        const u64* __restrict__ adjC,
        const unsigned char* __restrict__ occByte,
        int* __restrict__ indices,
        int* __restrict__ seedList,
        int* __restrict__ nclust,
        int n, int words) {
    __shared__ u64 S_l[64], R_l[64], occL[64];
    __shared__ int unresolved;
    __shared__ int wsS[64];
    int tid = threadIdx.x;              // 1024 = 16 waves
    int lane = tid & 63, wv = tid >> 6;

    for (int rb = wv; rb < 64; rb += 16) {
        unsigned char b = occByte[rb * 64 + lane];
        u64 m = __ballot(b != 0);
        if (lane == 0) occL[rb] = m;
    }
    if (tid < 64) {
        int base = tid << 6;
        int vb = n - base;
        u64 valid = (vb >= 64) ? ~0ull : ((vb <= 0) ? 0ull : ((1ull << vb) - 1ull));
        S_l[tid] = 0ull;
        R_l[tid] = ~valid;              // invalid tail = resolved nonseed
    }
    __syncthreads();

    // build pass: nzm (all nz words, for indices) + register-cached earlier rows
    u64 nzm[4];                 // full nonzero-word mask (indices phase)
    int eA[4], eB[4], eC[4];    // cached earlier-word ids (-1 = none)
    u64 rA[4], rB[4], rC[4];    // cached rows, pre-masked to earlier bits
    u64 restM[4];               // earlier words beyond cache (global fallback)
    #pragma unroll
    for (int k = 0; k < 4; ++k) {
        int i = (k << 10) + tid;
        u64 nz = 0ull, rest = 0ull;
        int cnt = 0;
        eA[k] = -1; eB[k] = -1; eC[k] = -1;
        rA[k] = 0ull; rB[k] = 0ull; rC[k] = 0ull;
        if (i < n) {
            int w_i = i >> 6, b_i = i & 63;
            u64 oc = occL[w_i];
            while (oc) {
                int e = (int)__ffsll(oc) - 1; oc &= oc - 1;
                if (e >= words) break;
                u64 row = adjC[(size_t)e * n + i];
                if (row) {
                    nz |= 1ull << e;
                    if (e <= w_i) {
                        u64 em = (e < w_i) ? ~0ull : (b_i ? ((1ull << b_i) - 1ull) : 0ull);
                        u64 re = row & em;
                        if (re) {
                            if      (cnt == 0) { eA[k] = e; rA[k] = re; }
                            else if (cnt == 1) { eB[k] = e; rB[k] = re; }
                            else if (cnt == 2) { eC[k] = e; rC[k] = re; }
                            else rest |= 1ull << e;
                            ++cnt;
                        }
                    }
                }
            }
        }
        nzm[k] = nz;
        restM[k] = rest;
    }

    unsigned done = 0;
    #pragma unroll
    for (int k = 0; k < 4; ++k)
        if (((k << 10) + tid) >= n) done |= 1u << k;

    for (;;) {
        if (tid == 0) unresolved = 0;
        unsigned pendSeed = 0, pendRes = 0;
        // ---- read phase (LDS + registers only; rare global fallback) ----
        #pragma unroll
        for (int k = 0; k < 4; ++k) {
            if (done & (1u << k)) continue;
            int i = (k << 10) + tid;
            int w_i = i >> 6, b_i = i & 63;
            u64 sA = 0ull, uA = 0ull;
            if (eA[k] >= 0) { sA |= rA[k] & S_l[eA[k]]; uA |= rA[k] & ~R_l[eA[k]]; }
            if (eB[k] >= 0) { sA |= rB[k] & S_l[eB[k]]; uA |= rB[k] & ~R_l[eB[k]]; }
            if (eC[k] >= 0) { sA |= rC[k] & S_l[eC[k]]; uA |= rC[k] & ~R_l[eC[k]]; }
            u64 rm = restM[k];
            while (rm) {
                int e = (int)__ffsll(rm) - 1; rm &= rm - 1;
                u64 row = adjC[(size_t)e * n + i];
                u64 em = (e < w_i) ? ~0ull : (b_i ? ((1ull << b_i) - 1ull) : 0ull);
                sA |= row & S_l[e] & em;
                uA |= row & ~R_l[e] & em;
            }
            if (sA) pendRes |= 1u << k;
            else if (!uA) { pendSeed |= 1u << k; pendRes |= 1u << k; }
        }
        __syncthreads();
        // ---- write phase: wave-aggregated (i&63 == lane) ----
        #pragma unroll
        for (int k = 0; k < 4; ++k) {
            u64 bS = __ballot((pendSeed >> k) & 1u);
            u64 bR = __ballot((pendRes  >> k) & 1u);
            int w_i = ((k << 10) + tid) >> 6;
            if (lane == 0 && w_i < 64) {
                if (bS) atomicOr(&S_l[w_i], bS);
                if (bR) atomicOr(&R_l[w_i], bR);
            }
        }
        done |= pendRes;
        if ((done & 0xFu) != 0xFu) unresolved = 1;
        __syncthreads();
        if (unresolved == 0) break;
    }

    if (tid < 64) {
        int pc = (int)__popcll(S_l[tid]);
        int x = pc;
        for (int o = 1; o < 64; o <<= 1) {
            int y = __shfl_up(x, o);
            if (tid >= o) x += y;
        }
        wsS[tid] = x - pc;
        if (tid == 63) *nclust = x;
    }
    __syncthreads();
    #pragma unroll
    for (int k = 0; k < 4; ++k) {
        int i = (k << 10) + tid;
        if (i >= n) continue;
        int best = -1;
        u64 m = nzm[k];
        while (m) {
            int e = (int)__ffsll(m) - 1; m &= m - 1;
            u64 s = adjC[(size_t)e * n + i] & S_l[e];
            if (s) best = (e << 6) + 63 - (int)__clzll(s);
        }
        int idx = 0;
        if (best >= 0) {
            int w2 = best >> 6, b = best & 63;
            u64 incl = (b >= 63) ? ~0ull : ((2ull << b) - 1ull);
            idx = wsS[w2] + (int)__popcll(S_l[w2] & incl);
        }
        indices[i] = idx;
        int wj = i >> 6, bj = i & 63;
        if ((S_l[wj] >> bj) & 1ull) {
            int rank = wsS[wj] + (int)__popcll(S_l[wj] & (bj ? ((1ull << bj) - 1ull) : 0ull)) + 1;
            seedList[rank - 1] = i;
        }
    }
}

// ---------------- Kernel 3: per-cluster fusion (LDS-staged, phase-split) ------
// All member data staged to LDS by 64 lanes; lane-0 serial math touches only
// LDS (identical arithmetic order => bit-identical). Transcendentals computed
// per-element in parallel (phase B/D), summed serially in the same order.
__global__ void fusion_kernel(const float* __restrict__ boxes,
                              const float* __restrict__ scores,
                              const int* __restrict__ indices,
                              const int* __restrict__ seedListG,
                              const int* __restrict__ nclust,
                              const u64* __restrict__ adjC,
                              float* __restrict__ fused,
                              float* __restrict__ sfused,
                              int* __restrict__ validArr, int n, int words) {
    int lane = threadIdx.x;       // 64 = 1 wave
    int nc = *nclust;
    __shared__ unsigned short js[256];
    __shared__ float ms[256];
    __shared__ float ds[256];
    __shared__ float bx[6][256];
    __shared__ float sv[256], cv[256], pw[256];
    __shared__ float refdirS, denomS;
    __shared__ int   flipS, mS;
    for (int i = blockIdx.x; i < n; i += gridDim.x) {
        int cid = i + 1;
        if (cid > nc) {
            if (lane < 7) fused[i*7+lane] = 0.0f;
            if (lane == 0) { sfused[i] = 0.0f; validArr[i] = 0; }
            continue;
        }
        int s = seedListG[i];
        u64 bits = (lane < words) ? adjC[(size_t)lane * n + s] : 0ull;
        // filter: keep only nodes whose final cluster is cid
        u64 keep = 0ull;
        u64 t = bits;
        while (t) {
            int b = (int)__ffsll(t) - 1;
            t &= t - 1;
            int node = (lane << 6) + b;
            if (indices[node] == cid) keep |= (1ull << b);
        }
        int cnt = __popcll(keep);
        int x = cnt;
        for (int o = 1; o < 64; o <<= 1) {
            int y = __shfl_up(x, o);
            if (lane >= o) x += y;
        }
        int excl = x - cnt;
        int m = __shfl(x, 63);
        int pos = excl;
        t = keep;
        while (t) {
            int b = (int)__ffsll(t) - 1;
            t &= t - 1;
            js[pos++] = (unsigned short)((lane << 6) + b);
        }
        __syncthreads();
        // stage ALL member data to LDS (parallel scattered loads)
        for (int k = lane; k < m; k += 64) {
            int j = js[k];
            ms[k] = scores[j];
            ds[k] = limit_period_f(boxes[j*7+6]);
            bx[0][k] = boxes[j*7+0];
            bx[1][k] = boxes[j*7+1];
            bx[2][k] = boxes[j*7+2];
            bx[3][k] = boxes[j*7+3];
            bx[4][k] = boxes[j*7+4];
            bx[5][k] = boxes[j*7+5];
        }
        __syncthreads();
        if (m == 0) {
            if (lane == 0) {
                for (int k = 0; k < 7; ++k) fused[i*7+k] = 0.0f;
                sfused[i] = 0.0f; validArr[i] = 0;
            }
            __syncthreads();
            continue;
        }
        // ---- phase A (lane 0, LDS-only): ssum/argmax/refdir/denom/flip ----
        if (lane == 0) {
            float ssum = 0.0f, smax = -1e30f; int kref = 0;
            for (int k = 0; k < m; ++k) {
                float sc = ms[k];
                ssum += sc;
                if (sc > smax) { smax = sc; kref = k; }
            }
            float refdir = ds[kref];
            float denom = fmaxf(ssum, 1e-12f);
            float sgt = 0.0f;
            for (int k = 0; k < m; ++k) {
                float d = fabsf(ds[k] - refdir);
                if (d > PI_F) d = TWO_PI_F - d;
                if (d > HALF_PI_F) sgt += ms[k];
            }
            float sle = ssum - sgt;
            refdirS = refdir; denomS = denom;
            flipS = (sgt <= sle) ? 1 : 0;
        }
        __syncthreads();
        // ---- phase B (parallel): per-element trig ----
        {
            float refdir = refdirS, denom = denomS;
            bool flipGt = flipS != 0;
            for (int k = lane; k < m; k += 64) {
                float dj = ds[k];
                float d = fabsf(dj - refdir);
                if (d > PI_F) d = TWO_PI_F - d;
                bool gt = d > HALF_PI_F;
                bool flip = flipGt ? gt : !gt;
                float adj_d = limit_period_f(dj + (flip ? PI_F : 0.0f));
                float wgt = ms[k] / denom;
                sv[k] = sinf(adj_d) * wgt;
                cv[k] = cosf(adj_d) * wgt;
            }
        }
        __syncthreads();
        // ---- phase C (lane 0): weighted sums + theta + sort ----
        if (lane == 0) {
            float denom = denomS;
            float cd0=0,cd1=0,cd2=0,cd3=0,cd4=0,cd5=0;
            for (int k = 0; k < m; ++k) {
                float wgt = ms[k] / denom;
                cd0 += wgt * bx[0][k];
                cd1 += wgt * bx[1][k];
                cd2 += wgt * bx[2][k];
                cd3 += wgt * bx[3][k];
                cd4 += wgt * bx[4][k];
                cd5 += wgt * bx[5][k];
            }
            float ssin = 0.0f, scos = 0.0f;
            for (int k = 0; k < m; ++k) { ssin += sv[k]; scos += cv[k]; }
            float theta = atan2f(ssin, scos);
            // sort member scores descending (serial, LDS)
            for (int k = 1; k < m; ++k) {
                float key = ms[k]; int p = k - 1;
                while (p >= 0 && ms[p] < key) { ms[p+1] = ms[p]; --p; }
                ms[p+1] = key;
            }
            // stash partial results for final phase
            bx[0][255] = cd0; bx[1][255] = cd1; bx[2][255] = cd2;
            bx[3][255] = cd3; bx[4][255] = cd4; bx[5][255] = cd5;
            sv[255] = theta;
            mS = m;
        }
        __syncthreads();
        // ---- phase D (parallel): powf on sorted scores ----
        for (int k = lane; k < m; k += 64)
            pw[k] = powf(ms[k], (float)(k+1));
        __syncthreads();
        // ---- phase E (lane 0): s_fused + corners + writes ----
        if (lane == 0) {
            float cd0 = bx[0][255], cd1 = bx[1][255], cd2 = bx[2][255];
            float cd3 = bx[3][255], cd4 = bx[4][255], cd5 = bx[5][255];
            float theta = sv[255];
            float sf = 0.0f;
            for (int k = 0; k < m; ++k) sf += pw[k];
            sf = fminf(sf, 1.0f);
            float c_ = cosf(theta), s_ = sinf(theta);
            float wdim = cd4, ldim = cd5;
            const float xs[4]  = {0.5f, 0.5f, -0.5f, -0.5f};
            const float ys_[4] = {-0.5f, 0.5f, 0.5f, -0.5f};
            bool inr = true;
            for (int c = 0; c < 4; ++c) {
                float cx = ldim * xs[c], cy = wdim * ys_[c];
                float rx = cx*c_ - cy*s_ + cd0;
                float ry = cx*s_ + cy*c_ + cd1;
                inr = inr && (rx > -140.8f) && (rx < 140.8f) && (ry > -40.0f) && (ry < 40.0f);
            }
            fused[i*7+0]=cd0; fused[i*7+1]=cd1; fused[i*7+2]=cd2;
            fused[i*7+3]=cd3; fused[i*7+4]=cd4; fused[i*7+5]=cd5;
            fused[i*7+6]=theta;
            sfused[i] = sf;
            validArr[i] = inr ? 1 : 0;
        }
        __syncthreads();
    }
}

// ---------------- Kernel 4: cumsum + gated output writes ----------------
__global__ void finalize_kernel(const float* __restrict__ fused,
                                const float* __restrict__ sfused,
                                const int* __restrict__ validArr,
                                const int* __restrict__ indices,
                                float* __restrict__ out, int n) {
    __shared__ int newidS[4096];
    __shared__ unsigned char validS[4096];
    __shared__ int scanBuf[1024];
    int tid = threadIdx.x;  // 1024
    int per = (n + 1023) >> 10;  // 4
    int base = tid * per;
    int v[8];
    int sum = 0;
    for (int k = 0; k < per && k < 8; ++k) {
        int j = base + k;
        int vv = (j < n) ? validArr[j] : 0;
        v[k] = vv; sum += vv;
    }
    scanBuf[tid] = sum;
    __syncthreads();
    for (int o = 1; o < 1024; o <<= 1) {
        int val = scanBuf[tid];
        int add = (tid >= o) ? scanBuf[tid - o] : 0;
        __syncthreads();
        scanBuf[tid] = val + add;
        __syncthreads();
    }
    int run = scanBuf[tid] - sum;
    for (int k = 0; k < per && k < 8; ++k) {
        int j = base + k;
        if (j < n) { run += v[k]; newidS[j] = run; validS[j] = (unsigned char)v[k]; }
    }
    __syncthreads();
    float* boxesO  = out;
    float* scoresO = out + (size_t)7*n;
    float* validO  = out + (size_t)8*n;
    float* idxO    = out + (size_t)9*n;
    for (int j = tid; j < n; j += 1024) {
        int vv = validS[j];
        #pragma unroll
        for (int k = 0; k < 7; ++k)
            boxesO[j*7+k] = vv ? fused[j*7+k] : 0.0f;
        scoresO[j] = vv ? sfused[j] : 0.0f;
        validO[j]  = vv ? 1.0f : 0.0f;
        int ind = indices[j];
        int safe = ind - 1; if (safe < 0) safe = 0;
        bool nv = (ind > 0) && (validS[safe] != 0);
        idxO[j] = nv ? (float)newidS[safe] : 0.0f;
    }
}

extern "C" void kernel_launch(void* const* d_in, const int* in_sizes, int n_in,
                              void* d_out, int out_size, void* d_ws, size_t ws_size,
                              hipStream_t stream) {
    const float* boxes  = (const float*)d_in[0];
    const float* scores = (const float*)d_in[1];
    int n = in_sizes[0] / 7;           // 4096
    int words = (n + 63) >> 6;         // 64

    char* ws = (char*)d_ws;
    size_t off = 0;
    u64* adjC = (u64*)(ws + off);
    off += (size_t)n * words * sizeof(u64);
    unsigned char* occByte = (unsigned char*)(ws + off); off += 64 * 64;
    int* seedList = (int*)(ws + off); off += (size_t)n * sizeof(int);
    int* indices  = (int*)(ws + off); off += (size_t)n * sizeof(int);
    float* fused  = (float*)(ws + off); off += (size_t)n * 7 * sizeof(float);
    float* sfused = (float*)(ws + off); off += (size_t)n * sizeof(float);
    int* validArr = (int*)(ws + off); off += (size_t)n * sizeof(int);
    int* nclust   = (int*)(ws + off); off += sizeof(int);

    dim3 adjGrid(words, (n + 255) / 256);
    adj_kernel<<<adjGrid, 256, 0, stream>>>(boxes, adjC, occByte, n, words);
    mis_node_kernel<<<1, 1024, 0, stream>>>(adjC, occByte, indices, seedList,
                                            nclust, n, words);
    fusion_kernel<<<512, 64, 0, stream>>>(boxes, scores, indices, seedList, nclust,
                                          adjC, fused, sfused, validArr, n, words);
    finalize_kernel<<<1, 1024, 0, stream>>>(fused, sfused, validArr, indices,
                                            (float*)d_out, n);
}

// Round 19
// 82.266 us; speedup vs baseline: 2.5047x; 1.1295x over previous
//
#include <hip/hip_runtime.h>
#include <math.h>

#define PI_F      3.141592653f
#define TWO_PI_F  6.283185306f
#define HALF_PI_F 1.5707963265f
#define IOU_THR_F 0.1f

typedef unsigned long long u64;

__device__ __forceinline__ float limit_period_f(float v) {
    return v - floorf(v / TWO_PI_F + 0.5f) * TWO_PI_F;
}

// ---------------- Kernel 1: adjacency + occByte (single-producer, no atomics) -
__global__ void adj_kernel(const float* __restrict__ boxes,
                           u64* __restrict__ adjC,
                           unsigned char* __restrict__ occByte,
                           int n, int words) {
    __shared__ float jS[7][64];
    int w = blockIdx.x;
    int tid = threadIdx.x;              // 256 = 4 waves
    int lane = tid & 63, wv = tid >> 6;
    if (tid < 64) {
        int j = (w << 6) + tid;
        if (j < n) {
            float b0 = boxes[j*7+0], b1 = boxes[j*7+1], b2 = boxes[j*7+2];
            float b3 = boxes[j*7+3], b4 = boxes[j*7+4], b5 = boxes[j*7+5];
            jS[0][tid] = b0 - b5*0.5f;  jS[3][tid] = b0 + b5*0.5f;
            jS[1][tid] = b1 - b4*0.5f;  jS[4][tid] = b1 + b4*0.5f;
            jS[2][tid] = b2 - b3*0.5f;  jS[5][tid] = b2 + b3*0.5f;
            jS[6][tid] = (b5*b4)*b3;
        }
    }
    __syncthreads();
    int i = blockIdx.y * 256 + tid;
    u64 word = 0ull;
    if (i < n) {
        float b0 = boxes[i*7+0], b1 = boxes[i*7+1], b2 = boxes[i*7+2];
        float b3 = boxes[i*7+3], b4 = boxes[i*7+4], b5 = boxes[i*7+5];
        float lix = b0 - b5*0.5f, hix = b0 + b5*0.5f;
        float liy = b1 - b4*0.5f, hiy = b1 + b4*0.5f;
        float liz = b2 - b3*0.5f, hiz = b2 + b3*0.5f;
        float vi  = (b5*b4)*b3;
        int jmax = n - (w << 6); if (jmax > 64) jmax = 64;
        for (int jj = 0; jj < jmax; ++jj) {
            float ix = fminf(hix, jS[3][jj]) - fmaxf(lix, jS[0][jj]); ix = fmaxf(ix, 0.0f);
            float iy = fminf(hiy, jS[4][jj]) - fmaxf(liy, jS[1][jj]); iy = fmaxf(iy, 0.0f);
            float iz = fminf(hiz, jS[5][jj]) - fmaxf(liz, jS[2][jj]); iz = fmaxf(iz, 0.0f);
            float inter = (ix*iy)*iz;
            float u = fmaxf(vi + jS[6][jj] - inter, 1e-8f);
            bool pred = (inter / u) > IOU_THR_F;
            word |= ((u64)(pred ? 1 : 0)) << jj;
        }
        adjC[(size_t)w * n + i] = word;
    }
    u64 bal = __ballot((i < n) && word != 0ull);
    int rb = blockIdx.y * 4 + wv;
    if (lane == 0 && rb < 64)
        occByte[rb * 64 + w] = bal ? (unsigned char)1 : (unsigned char)0;
}

// ---------------- Kernel 2: per-node row-cache prep (multi-block, coalesced) --
// For node i: ids+rows of its first 4 nonzero adjacency words (ascending) into
// column-major arrays (coalesced for both this writer and later readers);
// overflow words as a bitmask. Spread over 64 blocks -> latency hidden.
__global__ __launch_bounds__(64) void prep_kernel(
        const u64* __restrict__ adjC,
        const unsigned char* __restrict__ occByte,
        u64* __restrict__ cRow, unsigned* __restrict__ idPack,
        u64* __restrict__ restM, int n, int words) {
    int rb = blockIdx.x;           // 64 row-blocks
    int lane = threadIdx.x;        // 64
    int i = (rb << 6) + lane;
    unsigned char ob = occByte[rb * 64 + lane];
    u64 occR = __ballot(ob != 0);  // occupied words for this row-block (uniform)
    unsigned pack = 0xFFFFFFFFu;
    u64 rest = 0ull;
    u64 r0 = 0ull, r1 = 0ull, r2 = 0ull, r3 = 0ull;
    int cnt = 0;
    if (i < n) {
        u64 oc = occR;
        while (oc) {
            int e = (int)__ffsll(oc) - 1; oc &= oc - 1;
            if (e >= words) break;
            u64 row = adjC[(size_t)e * n + i];    // coalesced across lanes
            if (row) {
                if      (cnt == 0) { r0 = row; pack = (pack & 0xFFFFFF00u) | (unsigned)e; }
                else if (cnt == 1) { r1 = row; pack = (pack & 0xFFFF00FFu) | ((unsigned)e << 8); }
                else if (cnt == 2) { r2 = row; pack = (pack & 0xFF00FFFFu) | ((unsigned)e << 16); }
                else if (cnt == 3) { r3 = row; pack = (pack & 0x00FFFFFFu) | ((unsigned)e << 24); }
                else rest |= 1ull << e;
                ++cnt;
            }
        }
    }
    if (i < n) {
        cRow[(size_t)0 * n + i] = r0;
        cRow[(size_t)1 * n + i] = r1;
        cRow[(size_t)2 * n + i] = r2;
        cRow[(size_t)3 * n + i] = r3;
        idPack[i] = pack;
        restM[i]  = rest;
    }
}

// ---------------- Kernel 3: Jacobi fixpoint rounds only (1 block) -------------
// (R16-validated round logic.) seed(i) <=> no earlier neighbor of i is a seed.
// Rows come from prep arrays (coalesced load burst), rounds touch only
// LDS bitsets + registers. Outputs final seed bitset S[64].
__global__ __launch_bounds__(1024) void mis_round_kernel(
        const u64* __restrict__ adjC,
        const u64* __restrict__ cRow, const unsigned* __restrict__ idPack,
        const u64* __restrict__ restM,
        u64* __restrict__ SG, int n, int words) {
    __shared__ u64 S_l[64], R_l[64];
    __shared__ int unresolved;
    int tid = threadIdx.x;              // 1024 = 16 waves
    int lane = tid & 63;

    if (tid < 64) {
        int base = tid << 6;
        int vb = n - base;
        u64 valid = (vb >= 64) ? ~0ull : ((vb <= 0) ? 0ull : ((1ull << vb) - 1ull));
        S_l[tid] = 0ull;
        R_l[tid] = ~valid;              // invalid tail = resolved nonseed
    }
    __syncthreads();

    // coalesced load burst of per-node cached data
    int id0[4], id1[4], id2[4], id3[4];
    u64 r0[4], r1[4], r2[4], r3[4], rstR[4];
    #pragma unroll
    for (int k = 0; k < 4; ++k) {
        int i = (k << 10) + tid;
        id0[k] = id1[k] = id2[k] = id3[k] = 0xFF;
        r0[k] = r1[k] = r2[k] = r3[k] = 0ull; rstR[k] = 0ull;
        if (i < n) {
            unsigned p = idPack[i];
            id0[k] = (int)(p & 0xFFu);
            id1[k] = (int)((p >> 8) & 0xFFu);
            id2[k] = (int)((p >> 16) & 0xFFu);
            id3[k] = (int)((p >> 24) & 0xFFu);
            r0[k] = cRow[(size_t)0 * n + i];
            r1[k] = cRow[(size_t)1 * n + i];
            r2[k] = cRow[(size_t)2 * n + i];
            r3[k] = cRow[(size_t)3 * n + i];
            int w_i = i >> 6;
            u64 inclm = (w_i >= 63) ? ~0ull : ((2ull << w_i) - 1ull);
            rstR[k] = restM[i] & inclm;   // only earlier-or-same words matter
        }
    }

    unsigned done = 0;
    #pragma unroll
    for (int k = 0; k < 4; ++k)
        if (((k << 10) + tid) >= n) done |= 1u << k;

    for (;;) {
        if (tid == 0) unresolved = 0;
        unsigned pendSeed = 0, pendRes = 0;
        #pragma unroll
        for (int k = 0; k < 4; ++k) {
            if (done & (1u << k)) continue;
            int i = (k << 10) + tid;
            int w_i = i >> 6, b_i = i & 63;
            u64 lowm = b_i ? ((1ull << b_i) - 1ull) : 0ull;
            u64 sA = 0ull, uA = 0ull;
            #define RACC(IDV, RV) if (IDV != 0xFF && IDV <= w_i) { \
                u64 em = (IDV < w_i) ? ~0ull : lowm; \
                u64 mr = (RV) & em; \
                sA |= mr & S_l[IDV]; uA |= mr & ~R_l[IDV]; }
            RACC(id0[k], r0[k]) RACC(id1[k], r1[k])
            RACC(id2[k], r2[k]) RACC(id3[k], r3[k])
            #undef RACC
            u64 rm = rstR[k];
            while (rm) {
                int e = (int)__ffsll(rm) - 1; rm &= rm - 1;
                u64 row = adjC[(size_t)e * n + i];
                u64 em = (e < w_i) ? ~0ull : lowm;
                sA |= row & S_l[e] & em;
                uA |= row & ~R_l[e] & em;
            }
            if (sA) pendRes |= 1u << k;
            else if (!uA) { pendSeed |= 1u << k; pendRes |= 1u << k; }
        }
        __syncthreads();
        #pragma unroll
        for (int k = 0; k < 4; ++k) {
            u64 bS = __ballot((pendSeed >> k) & 1u);
            u64 bR = __ballot((pendRes  >> k) & 1u);
            int w_i = ((k << 10) + tid) >> 6;
            if (lane == 0 && w_i < 64) {
                if (bS) atomicOr(&S_l[w_i], bS);
                if (bR) atomicOr(&R_l[w_i], bR);
            }
        }
        done |= pendRes;
        if ((done & 0xFu) != 0xFu) unresolved = 1;
        __syncthreads();
        if (unresolved == 0) break;
    }
    if (tid < 64) SG[tid] = S_l[tid];
}

// ---------------- Kernel 4: indices + seedList + nclust (multi-block) ---------
// indices[j] = rank of max-index adjacent seed (last-writer-wins semantics);
// scan cached rows / overflow words descending. Coalesced per-node reads.
__global__ __launch_bounds__(64) void indices_kernel(
        const u64* __restrict__ adjC,
        const u64* __restrict__ SG,
        const u64* __restrict__ cRow, const unsigned* __restrict__ idPack,
        const u64* __restrict__ restM,
        int* __restrict__ indices, int* __restrict__ seedList,
        int* __restrict__ nclust, int n, int words) {
    __shared__ u64 S_s[64];
    __shared__ int ws_s[64];
    int lane = threadIdx.x;        // 64 = 1 wave
    u64 s = (lane < words) ? SG[lane] : 0ull;
    S_s[lane] = s;
    int pc = (int)__popcll(s);
    int x = pc;
    for (int o = 1; o < 64; o <<= 1) {
        int y = __shfl_up(x, o);
        if (lane >= o) x += y;
    }
    ws_s[lane] = x - pc;           // exclusive scan
    if (blockIdx.x == 0 && lane == 63) *nclust = x;
    __syncthreads();
    int i = blockIdx.x * 64 + lane;
    if (i >= n) return;
    unsigned p = idPack[i];
    u64 c0 = cRow[(size_t)0 * n + i];
    u64 c1 = cRow[(size_t)1 * n + i];
    u64 c2 = cRow[(size_t)2 * n + i];
    u64 c3 = cRow[(size_t)3 * n + i];
    int best = -1;
    // overflow words are higher than cached ids: scan descending first
    u64 rm = restM[i];
    while (rm) {
        int e = 63 - (int)__clzll(rm); rm &= ~(1ull << e);
        u64 s2 = adjC[(size_t)e * n + i] & S_s[e];
        if (s2) { best = (e << 6) + 63 - (int)__clzll(s2); break; }
    }
    if (best < 0) {
        #define ITRY(IDV, CV) if (best < 0 && (IDV) != 0xFFu) { \
            int e = (int)(IDV); \
            u64 s2 = (CV) & S_s[e]; \
            if (s2) best = (e << 6) + 63 - (int)__clzll(s2); }
        ITRY((p >> 24) & 0xFFu, c3)
        ITRY((p >> 16) & 0xFFu, c2)
        ITRY((p >> 8) & 0xFFu, c1)
        ITRY(p & 0xFFu, c0)
        #undef ITRY
    }
    int idx = 0;
    if (best >= 0) {
        int w2 = best >> 6, b = best & 63;
        u64 incl = (b >= 63) ? ~0ull : ((2ull << b) - 1ull);
        idx = ws_s[w2] + (int)__popcll(S_s[w2] & incl);   // 1-based cid
    }
    indices[i] = idx;
    int wj = i >> 6, bj = i & 63;
    if ((S_s[wj] >> bj) & 1ull) {
        int rank = ws_s[wj] + (int)__popcll(S_s[wj] & (bj ? ((1ull << bj) - 1ull) : 0ull)) + 1;
        seedList[rank - 1] = i;
    }
}

// ---------------- Kernel 5: per-cluster fusion (LDS-staged, phase-split) ------
__global__ void fusion_kernel(const float* __restrict__ boxes,
                              const float* __restrict__ scores,
                              const int* __restrict__ indices,
                              const int* __restrict__ seedListG,
                              const int* __restrict__ nclust,
                              const u64* __restrict__ adjC,
                              float* __restrict__ fused,
                              float* __restrict__ sfused,
                              int* __restrict__ validArr, int n, int words) {
    int lane = threadIdx.x;       // 64 = 1 wave
    int nc = *nclust;
    __shared__ unsigned short js[256];
    __shared__ float ms[256];
    __shared__ float ds[256];
    __shared__ float bx[6][256];
    __shared__ float sv[256], cv[256], pw[256];
    __shared__ float refdirS, denomS;
    __shared__ int   flipS, mS;
    for (int i = blockIdx.x; i < n; i += gridDim.x) {
        int cid = i + 1;
        if (cid > nc) {
            if (lane < 7) fused[i*7+lane] = 0.0f;
            if (lane == 0) { sfused[i] = 0.0f; validArr[i] = 0; }
            continue;
        }
        int s = seedListG[i];
        u64 bits = (lane < words) ? adjC[(size_t)lane * n + s] : 0ull;
        u64 keep = 0ull;
        u64 t = bits;
        while (t) {
            int b = (int)__ffsll(t) - 1;
            t &= t - 1;
            int node = (lane << 6) + b;
            if (indices[node] == cid) keep |= (1ull << b);
        }
        int cnt = __popcll(keep);
        int x = cnt;
        for (int o = 1; o < 64; o <<= 1) {
            int y = __shfl_up(x, o);
            if (lane >= o) x += y;
        }
        int excl = x - cnt;
        int m = __shfl(x, 63);
        int pos = excl;
        t = keep;
        while (t) {
            int b = (int)__ffsll(t) - 1;
            t &= t - 1;
            js[pos++] = (unsigned short)((lane << 6) + b);
        }
        __syncthreads();
        for (int k = lane; k < m; k += 64) {
            int j = js[k];
            ms[k] = scores[j];
            ds[k] = limit_period_f(boxes[j*7+6]);
            bx[0][k] = boxes[j*7+0];
            bx[1][k] = boxes[j*7+1];
            bx[2][k] = boxes[j*7+2];
            bx[3][k] = boxes[j*7+3];
            bx[4][k] = boxes[j*7+4];
            bx[5][k] = boxes[j*7+5];
        }
        __syncthreads();
        if (m == 0) {
            if (lane == 0) {
                for (int k = 0; k < 7; ++k) fused[i*7+k] = 0.0f;
                sfused[i] = 0.0f; validArr[i] = 0;
            }
            __syncthreads();
            continue;
        }
        if (lane == 0) {
            float ssum = 0.0f, smax = -1e30f; int kref = 0;
            for (int k = 0; k < m; ++k) {
                float sc = ms[k];
                ssum += sc;
                if (sc > smax) { smax = sc; kref = k; }
            }
            float refdir = ds[kref];
            float denom = fmaxf(ssum, 1e-12f);
            float sgt = 0.0f;
            for (int k = 0; k < m; ++k) {
                float d = fabsf(ds[k] - refdir);
                if (d > PI_F) d = TWO_PI_F - d;
                if (d > HALF_PI_F) sgt += ms[k];
            }
            float sle = ssum - sgt;
            refdirS = refdir; denomS = denom;
            flipS = (sgt <= sle) ? 1 : 0;
        }
        __syncthreads();
        {
            float refdir = refdirS, denom = denomS;
            bool flipGt = flipS != 0;
            for (int k = lane; k < m; k += 64) {
                float dj = ds[k];
                float d = fabsf(dj - refdir);
                if (d > PI_F) d = TWO_PI_F - d;
                bool gt = d > HALF_PI_F;
                bool flip = flipGt ? gt : !gt;
                float adj_d = limit_period_f(dj + (flip ? PI_F : 0.0f));
                float wgt = ms[k] / denom;
                sv[k] = sinf(adj_d) * wgt;
                cv[k] = cosf(adj_d) * wgt;
            }
        }
        __syncthreads();
        if (lane == 0) {
            float denom = denomS;
            float cd0=0,cd1=0,cd2=0,cd3=0,cd4=0,cd5=0;
            for (int k = 0; k < m; ++k) {
                float wgt = ms[k] / denom;
                cd0 += wgt * bx[0][k];
                cd1 += wgt * bx[1][k];
                cd2 += wgt * bx[2][k];
                cd3 += wgt * bx[3][k];
                cd4 += wgt * bx[4][k];
                cd5 += wgt * bx[5][k];
            }
            float ssin = 0.0f, scos = 0.0f;
            for (int k = 0; k < m; ++k) { ssin += sv[k]; scos += cv[k]; }
            float theta = atan2f(ssin, scos);
            for (int k = 1; k < m; ++k) {
                float key = ms[k]; int p = k - 1;
                while (p >= 0 && ms[p] < key) { ms[p+1] = ms[p]; --p; }
                ms[p+1] = key;
            }
            bx[0][255] = cd0; bx[1][255] = cd1; bx[2][255] = cd2;
            bx[3][255] = cd3; bx[4][255] = cd4; bx[5][255] = cd5;
            sv[255] = theta;
            mS = m;
        }
        __syncthreads();
        for (int k = lane; k < m; k += 64)
            pw[k] = powf(ms[k], (float)(k+1));
        __syncthreads();
        if (lane == 0) {
            float cd0 = bx[0][255], cd1 = bx[1][255], cd2 = bx[2][255];
            float cd3 = bx[3][255], cd4 = bx[4][255], cd5 = bx[5][255];
            float theta = sv[255];
            float sf = 0.0f;
            for (int k = 0; k < m; ++k) sf += pw[k];
            sf = fminf(sf, 1.0f);
            float c_ = cosf(theta), s_ = sinf(theta);
            float wdim = cd4, ldim = cd5;
            const float xs[4]  = {0.5f, 0.5f, -0.5f, -0.5f};
            const float ys_[4] = {-0.5f, 0.5f, 0.5f, -0.5f};
            bool inr = true;
            for (int c = 0; c < 4; ++c) {
                float cx = ldim * xs[c], cy = wdim * ys_[c];
                float rx = cx*c_ - cy*s_ + cd0;
                float ry = cx*s_ + cy*c_ + cd1;
                inr = inr && (rx > -140.8f) && (rx < 140.8f) && (ry > -40.0f) && (ry < 40.0f);
            }
            fused[i*7+0]=cd0; fused[i*7+1]=cd1; fused[i*7+2]=cd2;
            fused[i*7+3]=cd3; fused[i*7+4]=cd4; fused[i*7+5]=cd5;
            fused[i*7+6]=theta;
            sfused[i] = sf;
            validArr[i] = inr ? 1 : 0;
        }
        __syncthreads();
    }
}

// ---------------- Kernel 6: cumsum + gated output writes ----------------
__global__ void finalize_kernel(const float* __restrict__ fused,
                                const float* __restrict__ sfused,
                                const int* __restrict__ validArr,
                                const int* __restrict__ indices,
                                float* __restrict__ out, int n) {
    __shared__ int newidS[4096];
    __shared__ unsigned char validS[4096];
    __shared__ int scanBuf[1024];
    int tid = threadIdx.x;  // 1024
    int per = (n + 1023) >> 10;  // 4
    int base = tid * per;
    int v[8];
    int sum = 0;
    for (int k = 0; k < per && k < 8; ++k) {
        int j = base + k;
        int vv = (j < n) ? validArr[j] : 0;
        v[k] = vv; sum += vv;
    }
    scanBuf[tid] = sum;
    __syncthreads();
    for (int o = 1; o < 1024; o <<= 1) {
        int val = scanBuf[tid];
        int add = (tid >= o) ? scanBuf[tid - o] : 0;
        __syncthreads();
        scanBuf[tid] = val + add;
        __syncthreads();
    }
    int run = scanBuf[tid] - sum;
    for (int k = 0; k < per && k < 8; ++k) {
        int j = base + k;
        if (j < n) { run += v[k]; newidS[j] = run; validS[j] = (unsigned char)v[k]; }
    }
    __syncthreads();
    float* boxesO  = out;
    float* scoresO = out + (size_t)7*n;
    float* validO  = out + (size_t)8*n;
    float* idxO    = out + (size_t)9*n;
    for (int j = tid; j < n; j += 1024) {
        int vv = validS[j];
        #pragma unroll
        for (int k = 0; k < 7; ++k)
            boxesO[j*7+k] = vv ? fused[j*7+k] : 0.0f;
        scoresO[j] = vv ? sfused[j] : 0.0f;
        validO[j]  = vv ? 1.0f : 0.0f;
        int ind = indices[j];
        int safe = ind - 1; if (safe < 0) safe = 0;
        bool nv = (ind > 0) && (validS[safe] != 0);
        idxO[j] = nv ? (float)newidS[safe] : 0.0f;
    }
}

extern "C" void kernel_launch(void* const* d_in, const int* in_sizes, int n_in,
                              void* d_out, int out_size, void* d_ws, size_t ws_size,
                              hipStream_t stream) {
    const float* boxes  = (const float*)d_in[0];
    const float* scores = (const float*)d_in[1];
    int n = in_sizes[0] / 7;           // 4096
    int words = (n + 63) >> 6;         // 64

    char* ws = (char*)d_ws;
    size_t off = 0;
    u64* adjC = (u64*)(ws + off);
    off += (size_t)n * words * sizeof(u64);
    unsigned char* occByte = (unsigned char*)(ws + off); off += 64 * 64;
    u64* cRow   = (u64*)(ws + off); off += (size_t)4 * n * sizeof(u64);
    unsigned* idPack = (unsigned*)(ws + off); off += (size_t)n * sizeof(unsigned);
    u64* restM  = (u64*)(ws + off); off += (size_t)n * sizeof(u64);
    u64* SG     = (u64*)(ws + off); off += 64 * sizeof(u64);
    int* seedList = (int*)(ws + off); off += (size_t)n * sizeof(int);
    int* indices  = (int*)(ws + off); off += (size_t)n * sizeof(int);
    float* fused  = (float*)(ws + off); off += (size_t)n * 7 * sizeof(float);
    float* sfused = (float*)(ws + off); off += (size_t)n * sizeof(float);
    int* validArr = (int*)(ws + off); off += (size_t)n * sizeof(int);
    int* nclust   = (int*)(ws + off); off += sizeof(int);

    dim3 adjGrid(words, (n + 255) / 256);
    adj_kernel<<<adjGrid, 256, 0, stream>>>(boxes, adjC, occByte, n, words);
    prep_kernel<<<64, 64, 0, stream>>>(adjC, occByte, cRow, idPack, restM, n, words);
    mis_round_kernel<<<1, 1024, 0, stream>>>(adjC, cRow, idPack, restM, SG, n, words);
    indices_kernel<<<(n + 63) / 64, 64, 0, stream>>>(adjC, SG, cRow, idPack, restM,
                                                     indices, seedList, nclust, n, words);
    fusion_kernel<<<512, 64, 0, stream>>>(boxes, scores, indices, seedList, nclust,
                                          adjC, fused, sfused, validArr, n, words);
    finalize_kernel<<<1, 1024, 0, stream>>>(fused, sfused, validArr, indices,
                                            (float*)d_out, n);
}